// Round 1
// baseline (7001.241 us; speedup 1.0000x reference)
//
#include <hip/hip_runtime.h>

#define NN 100000

// ---------------- degree / norm ----------------
__global__ __launch_bounds__(256) void k_deg(const int* __restrict__ src,
    const int* __restrict__ dst, int* __restrict__ degO, int* __restrict__ degI, int E)
{
    int e = blockIdx.x * 256 + threadIdx.x;
    if (e < E) {
        atomicAdd(&degO[src[e]], 1);
        atomicAdd(&degI[dst[e]], 1);
    }
}

__global__ __launch_bounds__(256) void k_norm(const int* __restrict__ degO,
    const int* __restrict__ degI, float* __restrict__ ns, float* __restrict__ nd, int N)
{
    int n = blockIdx.x * 256 + threadIdx.x;
    if (n < N) {
        ns[n] = rsqrtf(fmaxf((float)degO[n], 1.0f));
        nd[n] = rsqrtf(fmaxf((float)degI[n], 1.0f));
    }
}

// ---------------- fused GEMM: out[n][:] = f(in[n][:]) @ W ----------------
// MODE 0: f(v) = v * norm_src[n]                         (layer-1 input = x)
// MODE 1: f(v) = relu(v * norm_dst[n] + bprev[k]) * norm_src[n]   (post-aggregation)
template<int DIN, int DOUT, int MODE>
__global__ __launch_bounds__(256) void k_gemm(
    const float* __restrict__ in, const float* __restrict__ W,
    const float* __restrict__ bprev,
    const float* __restrict__ norm_src, const float* __restrict__ norm_dst,
    float* __restrict__ out, int N)
{
    constexpr int BM = 64, BK = 32;
    constexpr int JPT = DOUT / 16;      // cols per thread: 8 (DOUT=128) or 4 (DOUT=64)
    __shared__ float As[BM][BK + 1];
    __shared__ float Bs[BK][DOUT];

    const int t  = threadIdx.x;
    const int tx = t & 15, ty = t >> 4;
    const int row0 = blockIdx.x * BM;

    float acc[4][JPT];
#pragma unroll
    for (int i = 0; i < 4; i++)
#pragma unroll
        for (int j = 0; j < JPT; j++) acc[i][j] = 0.0f;

    for (int k0 = 0; k0 < DIN; k0 += BK) {
        // ---- load A tile (with fused input epilogue) ----
#pragma unroll
        for (int p = 0; p < 2; p++) {
            int r  = p * 32 + (t >> 3);
            int kk = (t & 7) * 4;
            int n  = row0 + r;
            float4 v = make_float4(0.f, 0.f, 0.f, 0.f);
            if (n < N) {
                v = *(const float4*)&in[(size_t)n * DIN + k0 + kk];
                if (MODE == 1) {
                    float ndv = norm_dst[n], nsv = norm_src[n];
                    v.x = fmaxf(v.x * ndv + bprev[k0 + kk + 0], 0.f) * nsv;
                    v.y = fmaxf(v.y * ndv + bprev[k0 + kk + 1], 0.f) * nsv;
                    v.z = fmaxf(v.z * ndv + bprev[k0 + kk + 2], 0.f) * nsv;
                    v.w = fmaxf(v.w * ndv + bprev[k0 + kk + 3], 0.f) * nsv;
                } else {
                    float nsv = norm_src[n];
                    v.x *= nsv; v.y *= nsv; v.z *= nsv; v.w *= nsv;
                }
            }
            As[r][kk + 0] = v.x; As[r][kk + 1] = v.y;
            As[r][kk + 2] = v.z; As[r][kk + 3] = v.w;
        }
        // ---- load B tile ----
#pragma unroll
        for (int p = 0; p < BK * DOUT / 1024; p++) {
            int idx = p * 256 + t;          // float4 index
            int kk  = (idx * 4) / DOUT;
            int j   = (idx * 4) % DOUT;
            *(float4*)&Bs[kk][j] = *(const float4*)&W[(size_t)(k0 + kk) * DOUT + j];
        }
        __syncthreads();

#pragma unroll
        for (int kk = 0; kk < BK; kk++) {
            float a[4];
#pragma unroll
            for (int i = 0; i < 4; i++) a[i] = As[ty * 4 + i][kk];
            float b[JPT];
#pragma unroll
            for (int g = 0; g < JPT / 4; g++) {
                float4 bv = *(const float4*)&Bs[kk][g * 64 + tx * 4];
                b[g * 4 + 0] = bv.x; b[g * 4 + 1] = bv.y;
                b[g * 4 + 2] = bv.z; b[g * 4 + 3] = bv.w;
            }
#pragma unroll
            for (int i = 0; i < 4; i++)
#pragma unroll
                for (int j = 0; j < JPT; j++)
                    acc[i][j] += a[i] * b[j];
        }
        __syncthreads();
    }

    // ---- store ----
#pragma unroll
    for (int i = 0; i < 4; i++) {
        int n = row0 + ty * 4 + i;
        if (n < N) {
#pragma unroll
            for (int g = 0; g < JPT / 4; g++) {
                float4 v;
                v.x = acc[i][g * 4 + 0]; v.y = acc[i][g * 4 + 1];
                v.z = acc[i][g * 4 + 2]; v.w = acc[i][g * 4 + 3];
                *(float4*)&out[(size_t)n * DOUT + g * 64 + tx * 4] = v;
            }
        }
    }
}

// ---------------- edge gather + atomic scatter-add ----------------
template<int D>
__global__ __launch_bounds__(256) void k_edge(const int* __restrict__ src,
    const int* __restrict__ dst, const float* __restrict__ h,
    float* __restrict__ m, int E)
{
    constexpr int TPE = D / 4;                  // threads per edge
    constexpr int SH  = (D == 128) ? 5 : 4;     // log2(TPE)
    long gid = (long)blockIdx.x * 256 + threadIdx.x;
    if (gid >= (long)E * TPE) return;
    int e = (int)(gid >> SH);
    int c = ((int)gid & (TPE - 1)) * 4;
    int s = src[e], d = dst[e];
    const float4 v = *(const float4*)&h[(size_t)s * D + c];
    float* mp = &m[(size_t)d * D + c];
    atomicAdd(mp + 0, v.x);
    atomicAdd(mp + 1, v.y);
    atomicAdd(mp + 2, v.z);
    atomicAdd(mp + 3, v.w);
}

// ---------------- final epilogue: out = m * norm_dst + b3 ----------------
__global__ __launch_bounds__(256) void k_final(const float* __restrict__ m,
    const float* __restrict__ nd, const float* __restrict__ b3,
    float* __restrict__ out, int N)
{
    int idx4 = blockIdx.x * 256 + threadIdx.x;  // float4 index
    if (idx4 >= N * 64 / 4) return;
    int flat = idx4 * 4;
    int n = flat >> 6;
    int c = flat & 63;
    float4 v = *(const float4*)&m[flat];
    float ndv = nd[n];
    v.x = v.x * ndv + b3[c + 0];
    v.y = v.y * ndv + b3[c + 1];
    v.z = v.z * ndv + b3[c + 2];
    v.w = v.w * ndv + b3[c + 3];
    *(float4*)&out[flat] = v;
}

extern "C" void kernel_launch(void* const* d_in, const int* in_sizes, int n_in,
                              void* d_out, int out_size, void* d_ws, size_t ws_size,
                              hipStream_t stream) {
    const float* x  = (const float*)d_in[0];
    const int*   src = (const int*)d_in[1];
    const int*   dst = (const int*)d_in[2];
    const float* W1 = (const float*)d_in[3];
    const float* b1 = (const float*)d_in[4];
    const float* W2 = (const float*)d_in[5];
    const float* b2 = (const float*)d_in[6];
    const float* W3 = (const float*)d_in[7];
    const float* b3 = (const float*)d_in[8];
    float* out = (float*)d_out;

    const int N = NN;
    const int E = in_sizes[1];

    char* ws = (char*)d_ws;
    float* bufA = (float*)ws;                                   // N*128 f32
    float* bufB = (float*)(ws + (size_t)N * 128 * 4);           // N*128 f32
    float* ns   = (float*)(ws + (size_t)N * 128 * 4 * 2);       // N f32
    float* nd   = ns + N;                                       // N f32
    int*   degO = (int*)(nd + N);                               // N i32
    int*   degI = degO + N;                                     // N i32

    // degrees + norms
    hipMemsetAsync(degO, 0, (size_t)2 * N * 4, stream);
    k_deg<<<(E + 255) / 256, 256, 0, stream>>>(src, dst, degO, degI, E);
    k_norm<<<(N + 255) / 256, 256, 0, stream>>>(degO, degI, ns, nd, N);

    const int gemm_grid = (N + 63) / 64;
    const int eblk128 = (int)(((long)E * 32 + 255) / 256);
    const int eblk64  = (int)(((long)E * 16 + 255) / 256);

    // ---- layer 1 ----
    k_gemm<128, 128, 0><<<gemm_grid, 256, 0, stream>>>(x, W1, nullptr, ns, nd, bufA, N);
    hipMemsetAsync(bufB, 0, (size_t)N * 128 * 4, stream);
    k_edge<128><<<eblk128, 256, 0, stream>>>(src, dst, bufA, bufB, E);

    // ---- layer 2 (epilogue of layer 1 fused into A-load) ----
    k_gemm<128, 128, 1><<<gemm_grid, 256, 0, stream>>>(bufB, W2, b1, ns, nd, bufA, N);
    hipMemsetAsync(bufB, 0, (size_t)N * 128 * 4, stream);
    k_edge<128><<<eblk128, 256, 0, stream>>>(src, dst, bufA, bufB, E);

    // ---- layer 3 ----
    k_gemm<128, 64, 1><<<gemm_grid, 256, 0, stream>>>(bufB, W3, b2, ns, nd, bufA, N);
    hipMemsetAsync(bufB, 0, (size_t)N * 64 * 4, stream);
    k_edge<64><<<eblk64, 256, 0, stream>>>(src, dst, bufA, bufB, E);

    k_final<<<(N * 64 / 4 + 255) / 256, 256, 0, stream>>>(bufB, nd, b3, out, N);
}

// Round 2
// 706.384 us; speedup vs baseline: 9.9114x; 9.9114x over previous
//
#include <hip/hip_runtime.h>

#define NN 100000

// ---------------- degree count ----------------
__global__ __launch_bounds__(256) void k_deg(const int* __restrict__ src,
    const int* __restrict__ dst, int* __restrict__ degO, int* __restrict__ degI, int E)
{
    int e = blockIdx.x * 256 + threadIdx.x;
    if (e < E) {
        atomicAdd(&degO[src[e]], 1);
        atomicAdd(&degI[dst[e]], 1);
    }
}

__global__ __launch_bounds__(256) void k_norm(const int* __restrict__ degO,
    const int* __restrict__ degI, float* __restrict__ ns, float* __restrict__ nd, int N)
{
    int n = blockIdx.x * 256 + threadIdx.x;
    if (n < N) {
        ns[n] = rsqrtf(fmaxf((float)degO[n], 1.0f));
        nd[n] = rsqrtf(fmaxf((float)degI[n], 1.0f));
    }
}

// ---------------- hierarchical exclusive scan of degI -> rowptr ----------------
__global__ __launch_bounds__(256) void k_scan1(const int* __restrict__ cnt,
    int* __restrict__ part, int N)
{
    __shared__ int s[256];
    int t = threadIdx.x;
    int i = blockIdx.x * 256 + t;
    s[t] = (i < N) ? cnt[i] : 0;
    __syncthreads();
#pragma unroll
    for (int off = 128; off; off >>= 1) {
        if (t < off) s[t] += s[t + off];
        __syncthreads();
    }
    if (t == 0) part[blockIdx.x] = s[0];
}

__global__ __launch_bounds__(512) void k_scan2(int* __restrict__ part, int G)
{
    __shared__ int s[512];
    int t = threadIdx.x;
    int v = (t < G) ? part[t] : 0;
    s[t] = v;
    __syncthreads();
#pragma unroll
    for (int off = 1; off < 512; off <<= 1) {
        int x = (t >= off) ? s[t - off] : 0;
        __syncthreads();
        s[t] += x;
        __syncthreads();
    }
    if (t < G) part[t] = s[t] - v;   // exclusive
}

__global__ __launch_bounds__(256) void k_scan3(const int* __restrict__ cnt,
    const int* __restrict__ part, int* __restrict__ rowptr, int* __restrict__ cursor, int N)
{
    __shared__ int s[256];
    int t = threadIdx.x;
    int i = blockIdx.x * 256 + t;
    int v = (i < N) ? cnt[i] : 0;
    s[t] = v;
    __syncthreads();
#pragma unroll
    for (int off = 1; off < 256; off <<= 1) {
        int x = (t >= off) ? s[t - off] : 0;
        __syncthreads();
        s[t] += x;
        __syncthreads();
    }
    if (i < N) {
        int excl = s[t] - v + part[blockIdx.x];
        rowptr[i] = excl;
        cursor[i] = excl;
    }
}

// ---------------- edge placement: CSR by dst ----------------
__global__ __launch_bounds__(256) void k_scatter(const int* __restrict__ src,
    const int* __restrict__ dst, int* __restrict__ cursor, int* __restrict__ srcIdx, int E)
{
    int e = blockIdx.x * 256 + threadIdx.x;
    if (e < E) {
        int pos = atomicAdd(&cursor[dst[e]], 1);
        srcIdx[pos] = src[e];
    }
}

// ---------------- fused GEMM: out[n][:] = f(in[n][:]) @ W ----------------
// MODE 0: f(v) = v * norm_src[n]
// MODE 1: f(v) = relu(v * norm_dst[n] + bprev[k]) * norm_src[n]
template<int DIN, int DOUT, int MODE>
__global__ __launch_bounds__(256) void k_gemm(
    const float* __restrict__ in, const float* __restrict__ W,
    const float* __restrict__ bprev,
    const float* __restrict__ norm_src, const float* __restrict__ norm_dst,
    float* __restrict__ out, int N)
{
    constexpr int BM = 64, BK = 32;
    constexpr int JPT = DOUT / 16;
    __shared__ float As[BM][BK + 1];
    __shared__ float Bs[BK][DOUT];

    const int t  = threadIdx.x;
    const int tx = t & 15, ty = t >> 4;
    const int row0 = blockIdx.x * BM;

    float acc[4][JPT];
#pragma unroll
    for (int i = 0; i < 4; i++)
#pragma unroll
        for (int j = 0; j < JPT; j++) acc[i][j] = 0.0f;

    for (int k0 = 0; k0 < DIN; k0 += BK) {
#pragma unroll
        for (int p = 0; p < 2; p++) {
            int r  = p * 32 + (t >> 3);
            int kk = (t & 7) * 4;
            int n  = row0 + r;
            float4 v = make_float4(0.f, 0.f, 0.f, 0.f);
            if (n < N) {
                v = *(const float4*)&in[(size_t)n * DIN + k0 + kk];
                if (MODE == 1) {
                    float ndv = norm_dst[n], nsv = norm_src[n];
                    v.x = fmaxf(v.x * ndv + bprev[k0 + kk + 0], 0.f) * nsv;
                    v.y = fmaxf(v.y * ndv + bprev[k0 + kk + 1], 0.f) * nsv;
                    v.z = fmaxf(v.z * ndv + bprev[k0 + kk + 2], 0.f) * nsv;
                    v.w = fmaxf(v.w * ndv + bprev[k0 + kk + 3], 0.f) * nsv;
                } else {
                    float nsv = norm_src[n];
                    v.x *= nsv; v.y *= nsv; v.z *= nsv; v.w *= nsv;
                }
            }
            As[r][kk + 0] = v.x; As[r][kk + 1] = v.y;
            As[r][kk + 2] = v.z; As[r][kk + 3] = v.w;
        }
#pragma unroll
        for (int p = 0; p < BK * DOUT / 1024; p++) {
            int idx = p * 256 + t;
            int kk  = (idx * 4) / DOUT;
            int j   = (idx * 4) % DOUT;
            *(float4*)&Bs[kk][j] = *(const float4*)&W[(size_t)(k0 + kk) * DOUT + j];
        }
        __syncthreads();

#pragma unroll
        for (int kk = 0; kk < BK; kk++) {
            float a[4];
#pragma unroll
            for (int i = 0; i < 4; i++) a[i] = As[ty * 4 + i][kk];
            float b[JPT];
#pragma unroll
            for (int g = 0; g < JPT / 4; g++) {
                float4 bv = *(const float4*)&Bs[kk][g * 64 + tx * 4];
                b[g * 4 + 0] = bv.x; b[g * 4 + 1] = bv.y;
                b[g * 4 + 2] = bv.z; b[g * 4 + 3] = bv.w;
            }
#pragma unroll
            for (int i = 0; i < 4; i++)
#pragma unroll
                for (int j = 0; j < JPT; j++)
                    acc[i][j] += a[i] * b[j];
        }
        __syncthreads();
    }

#pragma unroll
    for (int i = 0; i < 4; i++) {
        int n = row0 + ty * 4 + i;
        if (n < N) {
#pragma unroll
            for (int g = 0; g < JPT / 4; g++) {
                float4 v;
                v.x = acc[i][g * 4 + 0]; v.y = acc[i][g * 4 + 1];
                v.z = acc[i][g * 4 + 2]; v.w = acc[i][g * 4 + 3];
                *(float4*)&out[(size_t)n * DOUT + g * 64 + tx * 4] = v;
            }
        }
    }
}

// ---------------- pull-based aggregation: m[n] = sum_{e in CSR[n]} h[srcIdx[e]] ----------------
// FINAL=1 additionally applies out = acc * nd[n] + b3[c]
template<int D, int FINAL>
__global__ __launch_bounds__(256) void k_agg(
    const int* __restrict__ rowptr, const int* __restrict__ cnt,
    const int* __restrict__ srcIdx, const float* __restrict__ h,
    const float* __restrict__ nd, const float* __restrict__ b3,
    float* __restrict__ m, int N)
{
    constexpr int TPN = D / 4;             // threads per node (32 or 16)
    constexpr int NPB = 256 / TPN;         // nodes per block (8 or 16)
    int t = threadIdx.x;
    int node = blockIdx.x * NPB + t / TPN;
    if (node >= N) return;
    int c = (t % TPN) * 4;

    int beg = rowptr[node];
    int end = beg + cnt[node];
    float4 acc = make_float4(0.f, 0.f, 0.f, 0.f);
    for (int e = beg; e < end; e++) {
        int s = srcIdx[e];
        float4 v = *(const float4*)&h[(size_t)s * D + c];
        acc.x += v.x; acc.y += v.y; acc.z += v.z; acc.w += v.w;
    }
    if (FINAL) {
        float ndv = nd[node];
        acc.x = acc.x * ndv + b3[c + 0];
        acc.y = acc.y * ndv + b3[c + 1];
        acc.z = acc.z * ndv + b3[c + 2];
        acc.w = acc.w * ndv + b3[c + 3];
    }
    *(float4*)&m[(size_t)node * D + c] = acc;
}

extern "C" void kernel_launch(void* const* d_in, const int* in_sizes, int n_in,
                              void* d_out, int out_size, void* d_ws, size_t ws_size,
                              hipStream_t stream) {
    const float* x  = (const float*)d_in[0];
    const int*   src = (const int*)d_in[1];
    const int*   dst = (const int*)d_in[2];
    const float* W1 = (const float*)d_in[3];
    const float* b1 = (const float*)d_in[4];
    const float* W2 = (const float*)d_in[5];
    const float* b2 = (const float*)d_in[6];
    const float* W3 = (const float*)d_in[7];
    const float* b3 = (const float*)d_in[8];
    float* out = (float*)d_out;

    const int N = NN;
    const int E = in_sizes[1];
    const int G = (N + 255) / 256;          // scan blocks (391)

    char* ws = (char*)d_ws;
    float* bufA  = (float*)ws;                                  // N*128 f32
    float* bufB  = (float*)(ws + (size_t)N * 128 * 4);          // N*128 f32
    char*  p     = ws + (size_t)N * 128 * 4 * 2;
    float* ns    = (float*)p;              p += (size_t)N * 4;
    float* nd    = (float*)p;              p += (size_t)N * 4;
    int*   degO  = (int*)p;                p += (size_t)N * 4;
    int*   degI  = (int*)p;                p += (size_t)N * 4;
    int*   rowp  = (int*)p;                p += (size_t)N * 4;
    int*   curs  = (int*)p;                p += (size_t)N * 4;
    int*   part  = (int*)p;                p += (size_t)512 * 4;
    int*   srcIdx= (int*)p;                                     // E int

    // degrees + norms
    hipMemsetAsync(degO, 0, (size_t)2 * N * 4, stream);
    k_deg<<<(E + 255) / 256, 256, 0, stream>>>(src, dst, degO, degI, E);
    k_norm<<<G, 256, 0, stream>>>(degO, degI, ns, nd, N);

    // CSR build (by dst)
    k_scan1<<<G, 256, 0, stream>>>(degI, part, N);
    k_scan2<<<1, 512, 0, stream>>>(part, G);
    k_scan3<<<G, 256, 0, stream>>>(degI, part, rowp, curs, N);
    k_scatter<<<(E + 255) / 256, 256, 0, stream>>>(src, dst, curs, srcIdx, E);

    const int gemm_grid = (N + 63) / 64;
    const int agg128 = (N + 7) / 8;
    const int agg64  = (N + 15) / 16;

    // ---- layer 1 ----
    k_gemm<128, 128, 0><<<gemm_grid, 256, 0, stream>>>(x, W1, nullptr, ns, nd, bufA, N);
    k_agg<128, 0><<<agg128, 256, 0, stream>>>(rowp, degI, srcIdx, bufA, nd, b3, bufB, N);

    // ---- layer 2 ----
    k_gemm<128, 128, 1><<<gemm_grid, 256, 0, stream>>>(bufB, W2, b1, ns, nd, bufA, N);
    k_agg<128, 0><<<agg128, 256, 0, stream>>>(rowp, degI, srcIdx, bufA, nd, b3, bufB, N);

    // ---- layer 3 (final epilogue fused) ----
    k_gemm<128, 64, 1><<<gemm_grid, 256, 0, stream>>>(bufB, W3, b2, ns, nd, bufA, N);
    k_agg<64, 1><<<agg64, 256, 0, stream>>>(rowp, degI, srcIdx, bufA, nd, b3, out, N);
}

// Round 3
// 643.213 us; speedup vs baseline: 10.8848x; 1.0982x over previous
//
#include <hip/hip_runtime.h>

#define NN 100000

typedef short short8 __attribute__((ext_vector_type(8)));
typedef float f32x4 __attribute__((ext_vector_type(4)));

__device__ inline unsigned short f2bf(float x) {
    unsigned u = __float_as_uint(x);
    unsigned r = (u + 0x7FFF + ((u >> 16) & 1)) >> 16;
    return (unsigned short)r;
}
__device__ inline float bf2f(unsigned short h) {
    return __uint_as_float(((unsigned)h) << 16);
}

// ---------------- degree count ----------------
__global__ __launch_bounds__(256) void k_deg(const int* __restrict__ src,
    const int* __restrict__ dst, int* __restrict__ degO, int* __restrict__ degI, int E)
{
    int e = blockIdx.x * 256 + threadIdx.x;
    if (e < E) {
        atomicAdd(&degO[src[e]], 1);
        atomicAdd(&degI[dst[e]], 1);
    }
}

__global__ __launch_bounds__(256) void k_norm(const int* __restrict__ degO,
    const int* __restrict__ degI, float* __restrict__ ns, float* __restrict__ nd, int N)
{
    int n = blockIdx.x * 256 + threadIdx.x;
    if (n < N) {
        ns[n] = rsqrtf(fmaxf((float)degO[n], 1.0f));
        nd[n] = rsqrtf(fmaxf((float)degI[n], 1.0f));
    }
}

// ---------------- hierarchical exclusive scan of degI -> rowptr ----------------
__global__ __launch_bounds__(256) void k_scan1(const int* __restrict__ cnt,
    int* __restrict__ part, int N)
{
    __shared__ int s[256];
    int t = threadIdx.x;
    int i = blockIdx.x * 256 + t;
    s[t] = (i < N) ? cnt[i] : 0;
    __syncthreads();
#pragma unroll
    for (int off = 128; off; off >>= 1) {
        if (t < off) s[t] += s[t + off];
        __syncthreads();
    }
    if (t == 0) part[blockIdx.x] = s[0];
}

__global__ __launch_bounds__(512) void k_scan2(int* __restrict__ part, int G)
{
    __shared__ int s[512];
    int t = threadIdx.x;
    int v = (t < G) ? part[t] : 0;
    s[t] = v;
    __syncthreads();
#pragma unroll
    for (int off = 1; off < 512; off <<= 1) {
        int x = (t >= off) ? s[t - off] : 0;
        __syncthreads();
        s[t] += x;
        __syncthreads();
    }
    if (t < G) part[t] = s[t] - v;   // exclusive
}

__global__ __launch_bounds__(256) void k_scan3(const int* __restrict__ cnt,
    const int* __restrict__ part, int* __restrict__ rowptr, int* __restrict__ cursor, int N)
{
    __shared__ int s[256];
    int t = threadIdx.x;
    int i = blockIdx.x * 256 + t;
    int v = (i < N) ? cnt[i] : 0;
    s[t] = v;
    __syncthreads();
#pragma unroll
    for (int off = 1; off < 256; off <<= 1) {
        int x = (t >= off) ? s[t - off] : 0;
        __syncthreads();
        s[t] += x;
        __syncthreads();
    }
    if (i < N) {
        int excl = s[t] - v + part[blockIdx.x];
        rowptr[i] = excl;
        cursor[i] = excl;
    }
}

// ---------------- edge placement: CSR by dst ----------------
__global__ __launch_bounds__(256) void k_scatter(const int* __restrict__ src,
    const int* __restrict__ dst, int* __restrict__ cursor, int* __restrict__ srcIdx, int E)
{
    int e = blockIdx.x * 256 + threadIdx.x;
    if (e < E) {
        int pos = atomicAdd(&cursor[dst[e]], 1);
        srcIdx[pos] = src[e];
    }
}

// ---------------- W prep: transpose + bf16 split + XOR-swizzle ----------------
// W[128][DOUT] f32  ->  Wt[c][k] (c=0..DOUT-1 rows, 128 k, 2B), byte-in-row ^= (c&7)<<4
template<int DOUT>
__global__ __launch_bounds__(256) void k_prepW(const float* __restrict__ W,
    unsigned short* __restrict__ Wh, unsigned short* __restrict__ Wl)
{
    int idx = blockIdx.x * 256 + threadIdx.x;
    if (idx >= 128 * DOUT) return;
    int c = idx % DOUT;
    int k = idx / DOUT;
    float w = W[idx];
    unsigned short hi = f2bf(w);
    unsigned short lo = f2bf(w - bf2f(hi));
    int boff = c * 256 + ((2 * k) ^ ((c & 7) << 4));
    *(unsigned short*)((char*)Wh + boff) = hi;
    *(unsigned short*)((char*)Wl + boff) = lo;
}

// ---------------- MFMA GEMM: out[n][:] = f(in[n][:]) @ W  (DIN=128) ----------------
// MODE 0: f(v) = v * ns[n];  MODE 1: f(v) = relu(v * nd[n] + bprev[k]) * ns[n]
template<int DOUT, int MODE>
__global__ __launch_bounds__(256) void k_gemm_mfma(
    const float* __restrict__ in,
    const unsigned short* __restrict__ Wth, const unsigned short* __restrict__ Wtl,
    const float* __restrict__ bprev,
    const float* __restrict__ ns, const float* __restrict__ nd,
    float* __restrict__ out, int N)
{
    constexpr int NT = DOUT / 16;               // n-tiles: 8 or 4
    __shared__ __align__(16) unsigned short Wh[DOUT * 128];
    __shared__ __align__(16) unsigned short Wl[DOUT * 128];

    const int t = threadIdx.x;
    const int w = t >> 6, l = t & 63;

    // stage W (pre-swizzled, linear copy) into LDS
#pragma unroll
    for (int i = 0; i < DOUT * 256 / 4096; i++) {
        int off = i * 4096 + t * 16;
        *(float4*)((char*)Wh + off) = *(const float4*)((const char*)Wth + off);
        *(float4*)((char*)Wl + off) = *(const float4*)((const char*)Wtl + off);
    }

    const int rl   = l & 15;        // row within 16-tile
    const int kgrp = l >> 4;        // 0..3
    const int row  = blockIdx.x * 64 + w * 16 + rl;
    const int rowc = row < N ? row : N - 1;
    const float* arow = in + (size_t)rowc * 128;

    // ---- load A rows, fused input epilogue, split to bf16 hi/lo ----
    float av[4][8];
#pragma unroll
    for (int ks = 0; ks < 4; ks++) {
        int kb = ks * 32 + kgrp * 8;
        float4 v0 = *(const float4*)(arow + kb);
        float4 v1 = *(const float4*)(arow + kb + 4);
        av[ks][0] = v0.x; av[ks][1] = v0.y; av[ks][2] = v0.z; av[ks][3] = v0.w;
        av[ks][4] = v1.x; av[ks][5] = v1.y; av[ks][6] = v1.z; av[ks][7] = v1.w;
    }
    if (MODE == 1) {
        float ndv = nd[rowc], nsv = ns[rowc];
#pragma unroll
        for (int ks = 0; ks < 4; ks++) {
            int kb = ks * 32 + kgrp * 8;
            float4 b0 = *(const float4*)(bprev + kb);
            float4 b1 = *(const float4*)(bprev + kb + 4);
            float bb[8] = {b0.x, b0.y, b0.z, b0.w, b1.x, b1.y, b1.z, b1.w};
#pragma unroll
            for (int j = 0; j < 8; j++)
                av[ks][j] = fmaxf(av[ks][j] * ndv + bb[j], 0.f) * nsv;
        }
    } else {
        float nsv = ns[rowc];
#pragma unroll
        for (int ks = 0; ks < 4; ks++)
#pragma unroll
            for (int j = 0; j < 8; j++)
                av[ks][j] *= nsv;
    }
    short8 Ah[4], Al[4];
#pragma unroll
    for (int ks = 0; ks < 4; ks++)
#pragma unroll
        for (int j = 0; j < 8; j++) {
            unsigned short hi = f2bf(av[ks][j]);
            Ah[ks][j] = (short)hi;
            Al[ks][j] = (short)f2bf(av[ks][j] - bf2f(hi));
        }

    __syncthreads();

    // ---- MFMA main: acc = Ah*Wh + Al*Wh + Ah*Wl ----
    f32x4 acc[NT];
#pragma unroll
    for (int tt = 0; tt < NT; tt++) acc[tt] = (f32x4){0.f, 0.f, 0.f, 0.f};

#pragma unroll
    for (int ks = 0; ks < 4; ks++) {
        int kbyte = ks * 64 + kgrp * 16;    // byte offset of this lane's 8 bf16 within a row
#pragma unroll
        for (int tt = 0; tt < NT; tt++) {
            int c = tt * 16 + rl;
            int boff = c * 256 + (kbyte ^ ((c & 7) << 4));
            short8 Bh = *(short8*)((char*)Wh + boff);
            short8 Bl = *(short8*)((char*)Wl + boff);
            acc[tt] = __builtin_amdgcn_mfma_f32_16x16x32_bf16(Ah[ks], Bh, acc[tt], 0, 0, 0);
            acc[tt] = __builtin_amdgcn_mfma_f32_16x16x32_bf16(Al[ks], Bh, acc[tt], 0, 0, 0);
            acc[tt] = __builtin_amdgcn_mfma_f32_16x16x32_bf16(Ah[ks], Bl, acc[tt], 0, 0, 0);
        }
    }

    // ---- store: lane l, reg r -> row kgrp*4+r, col tt*16+rl ----
    const int orow = blockIdx.x * 64 + w * 16 + kgrp * 4;
#pragma unroll
    for (int r = 0; r < 4; r++) {
        if (orow + r < N) {
#pragma unroll
            for (int tt = 0; tt < NT; tt++)
                out[(size_t)(orow + r) * DOUT + tt * 16 + rl] = acc[tt][r];
        }
    }
}

// ---------------- pull-based aggregation ----------------
template<int D, int FINAL>
__global__ __launch_bounds__(256) void k_agg(
    const int* __restrict__ rowptr, const int* __restrict__ cnt,
    const int* __restrict__ srcIdx, const float* __restrict__ h,
    const float* __restrict__ nd, const float* __restrict__ b3,
    float* __restrict__ m, int N)
{
    constexpr int TPN = D / 4;
    constexpr int NPB = 256 / TPN;
    int t = threadIdx.x;
    int node = blockIdx.x * NPB + t / TPN;
    if (node >= N) return;
    int c = (t % TPN) * 4;

    int beg = rowptr[node];
    int end = beg + cnt[node];
    float4 acc = make_float4(0.f, 0.f, 0.f, 0.f);
    for (int e = beg; e < end; e++) {
        int s = srcIdx[e];
        float4 v = *(const float4*)&h[(size_t)s * D + c];
        acc.x += v.x; acc.y += v.y; acc.z += v.z; acc.w += v.w;
    }
    if (FINAL) {
        float ndv = nd[node];
        acc.x = acc.x * ndv + b3[c + 0];
        acc.y = acc.y * ndv + b3[c + 1];
        acc.z = acc.z * ndv + b3[c + 2];
        acc.w = acc.w * ndv + b3[c + 3];
    }
    *(float4*)&m[(size_t)node * D + c] = acc;
}

extern "C" void kernel_launch(void* const* d_in, const int* in_sizes, int n_in,
                              void* d_out, int out_size, void* d_ws, size_t ws_size,
                              hipStream_t stream) {
    const float* x  = (const float*)d_in[0];
    const int*   src = (const int*)d_in[1];
    const int*   dst = (const int*)d_in[2];
    const float* W1 = (const float*)d_in[3];
    const float* b1 = (const float*)d_in[4];
    const float* W2 = (const float*)d_in[5];
    const float* b2 = (const float*)d_in[6];
    const float* W3 = (const float*)d_in[7];
    const float* b3 = (const float*)d_in[8];
    float* out = (float*)d_out;

    const int N = NN;
    const int E = in_sizes[1];
    const int G = (N + 255) / 256;

    char* ws = (char*)d_ws;
    float* bufA  = (float*)ws;                                  // N*128 f32
    float* bufB  = (float*)(ws + (size_t)N * 128 * 4);          // N*128 f32
    char*  p     = ws + (size_t)N * 128 * 4 * 2;
    float* ns    = (float*)p;              p += (size_t)N * 4;
    float* nd    = (float*)p;              p += (size_t)N * 4;
    int*   degO  = (int*)p;                p += (size_t)N * 4;
    int*   degI  = (int*)p;                p += (size_t)N * 4;
    int*   rowp  = (int*)p;                p += (size_t)N * 4;
    int*   curs  = (int*)p;                p += (size_t)N * 4;
    int*   part  = (int*)p;                p += (size_t)512 * 4;
    int*   srcIdx= (int*)p;                p += (size_t)E * 4;
    unsigned short* W1h = (unsigned short*)p; p += 128 * 128 * 2;
    unsigned short* W1l = (unsigned short*)p; p += 128 * 128 * 2;
    unsigned short* W2h = (unsigned short*)p; p += 128 * 128 * 2;
    unsigned short* W2l = (unsigned short*)p; p += 128 * 128 * 2;
    unsigned short* W3h = (unsigned short*)p; p += 64 * 128 * 2;
    unsigned short* W3l = (unsigned short*)p; p += 64 * 128 * 2;

    // W prep (independent of everything else)
    k_prepW<128><<<64, 256, 0, stream>>>(W1, W1h, W1l);
    k_prepW<128><<<64, 256, 0, stream>>>(W2, W2h, W2l);
    k_prepW<64><<<32, 256, 0, stream>>>(W3, W3h, W3l);

    // degrees + norms
    hipMemsetAsync(degO, 0, (size_t)2 * N * 4, stream);
    k_deg<<<(E + 255) / 256, 256, 0, stream>>>(src, dst, degO, degI, E);
    k_norm<<<G, 256, 0, stream>>>(degO, degI, ns, nd, N);

    // CSR build (by dst)
    k_scan1<<<G, 256, 0, stream>>>(degI, part, N);
    k_scan2<<<1, 512, 0, stream>>>(part, G);
    k_scan3<<<G, 256, 0, stream>>>(degI, part, rowp, curs, N);
    k_scatter<<<(E + 255) / 256, 256, 0, stream>>>(src, dst, curs, srcIdx, E);

    const int gemm_grid = (N + 63) / 64;
    const int agg128 = (N + 7) / 8;
    const int agg64  = (N + 15) / 16;

    // ---- layer 1 ----
    k_gemm_mfma<128, 0><<<gemm_grid, 256, 0, stream>>>(x, W1h, W1l, nullptr, ns, nd, bufA, N);
    k_agg<128, 0><<<agg128, 256, 0, stream>>>(rowp, degI, srcIdx, bufA, nd, b3, bufB, N);

    // ---- layer 2 ----
    k_gemm_mfma<128, 1><<<gemm_grid, 256, 0, stream>>>(bufB, W2h, W2l, b1, ns, nd, bufA, N);
    k_agg<128, 0><<<agg128, 256, 0, stream>>>(rowp, degI, srcIdx, bufA, nd, b3, bufB, N);

    // ---- layer 3 (final epilogue fused) ----
    k_gemm_mfma<64, 1><<<gemm_grid, 256, 0, stream>>>(bufB, W3h, W3l, b2, ns, nd, bufA, N);
    k_agg<64, 1><<<agg64, 256, 0, stream>>>(rowp, degI, srcIdx, bufA, nd, b3, out, N);
}

// Round 4
// 631.708 us; speedup vs baseline: 11.0830x; 1.0182x over previous
//
#include <hip/hip_runtime.h>

#define NN 100000
#define NB 196            // (NN + 511) >> 9 buckets of 512 nodes
#define PB_BLOCKS 96      // blocks in k_bscatter

typedef short short8 __attribute__((ext_vector_type(8)));
typedef float f32x4 __attribute__((ext_vector_type(4)));

__device__ inline unsigned short f2bf(float x) {
    unsigned u = __float_as_uint(x);
    unsigned r = (u + 0x7FFF + ((u >> 16) & 1)) >> 16;
    return (unsigned short)r;
}
__device__ inline float bf2f(unsigned short h) {
    return __uint_as_float(((unsigned)h) << 16);
}

// ---------------- degree count ----------------
__global__ __launch_bounds__(256) void k_deg(const int* __restrict__ src,
    const int* __restrict__ dst, int* __restrict__ degO, int* __restrict__ degI, int E)
{
    int e = blockIdx.x * 256 + threadIdx.x;
    if (e < E) {
        atomicAdd(&degO[src[e]], 1);
        atomicAdd(&degI[dst[e]], 1);
    }
}

__global__ __launch_bounds__(256) void k_norm(const int* __restrict__ degO,
    const int* __restrict__ degI, float* __restrict__ ns, float* __restrict__ nd, int N)
{
    int n = blockIdx.x * 256 + threadIdx.x;
    if (n < N) {
        ns[n] = rsqrtf(fmaxf((float)degO[n], 1.0f));
        nd[n] = rsqrtf(fmaxf((float)degI[n], 1.0f));
    }
}

// ---------------- hierarchical exclusive scan of degI -> rowptr ----------------
__global__ __launch_bounds__(256) void k_scan1(const int* __restrict__ cnt,
    int* __restrict__ part, int N)
{
    __shared__ int s[256];
    int t = threadIdx.x;
    int i = blockIdx.x * 256 + t;
    s[t] = (i < N) ? cnt[i] : 0;
    __syncthreads();
#pragma unroll
    for (int off = 128; off; off >>= 1) {
        if (t < off) s[t] += s[t + off];
        __syncthreads();
    }
    if (t == 0) part[blockIdx.x] = s[0];
}

__global__ __launch_bounds__(512) void k_scan2(int* __restrict__ part, int G)
{
    __shared__ int s[512];
    int t = threadIdx.x;
    int v = (t < G) ? part[t] : 0;
    s[t] = v;
    __syncthreads();
#pragma unroll
    for (int off = 1; off < 512; off <<= 1) {
        int x = (t >= off) ? s[t - off] : 0;
        __syncthreads();
        s[t] += x;
        __syncthreads();
    }
    if (t < G) part[t] = s[t] - v;   // exclusive
}

__global__ __launch_bounds__(256) void k_scan3(const int* __restrict__ cnt,
    const int* __restrict__ part, int* __restrict__ rowptr, int N)
{
    __shared__ int s[256];
    int t = threadIdx.x;
    int i = blockIdx.x * 256 + t;
    int v = (i < N) ? cnt[i] : 0;
    s[t] = v;
    __syncthreads();
#pragma unroll
    for (int off = 1; off < 256; off <<= 1) {
        int x = (t >= off) ? s[t - off] : 0;
        __syncthreads();
        s[t] += x;
        __syncthreads();
    }
    if (i < N) rowptr[i] = s[t] - v + part[blockIdx.x];
}

// ---------------- bucket histogram from degI ----------------
__global__ __launch_bounds__(256) void k_bhist(const int* __restrict__ degI,
    int* __restrict__ bcnt, int N)
{
    __shared__ int s[256];
    int b = blockIdx.x, t = threadIdx.x;
    int sum = 0;
    for (int i = t; i < 512; i += 256) {
        int n = (b << 9) + i;
        if (n < N) sum += degI[n];
    }
    s[t] = sum;
    __syncthreads();
#pragma unroll
    for (int off = 128; off; off >>= 1) {
        if (t < off) s[t] += s[t + off];
        __syncthreads();
    }
    if (t == 0) bcnt[b] = s[0];
}

// ---------------- bucket scan: 16-aligned bases + garbage headroom ----------------
__global__ __launch_bounds__(256) void k_bscan(const int* __restrict__ bcnt,
    int* __restrict__ bbase, int* __restrict__ gcur)
{
    __shared__ int s[256];
    int t = threadIdx.x;
    int sz = 0;
    if (t < NB) sz = ((bcnt[t] + 15) & ~15) + 16 * PB_BLOCKS;
    s[t] = sz;
    __syncthreads();
#pragma unroll
    for (int off = 1; off < 256; off <<= 1) {
        int x = (t >= off) ? s[t - off] : 0;
        __syncthreads();
        s[t] += x;
        __syncthreads();
    }
    if (t < NB) {
        int e = s[t] - sz;
        bbase[t] = e;
        gcur[t] = e;
    }
}

// ---------------- Pass B: LDS-staged bucket scatter (full-line writes) ----------------
__global__ __launch_bounds__(256) void k_bscatter(const int* __restrict__ src,
    const int* __restrict__ dst, int* __restrict__ gcur, unsigned* __restrict__ tmp, int E)
{
    __shared__ unsigned stg[256][16];
    __shared__ int lcnt[256];
    __shared__ int anyPend;
    int t = threadIdx.x;
    lcnt[t] = 0;

    int chunk = (E + PB_BLOCKS - 1) / PB_BLOCKS;
    int e0 = blockIdx.x * chunk;
    int e1 = min(E, e0 + chunk);

    for (int base = e0; base < e1; base += 256) {
        int e = base + t;
        bool pending = e < e1;
        unsigned val = 0;
        int b = 0;
        if (pending) {
            int s_ = src[e], d_ = dst[e];
            b = d_ >> 9;
            val = (unsigned)s_ | ((unsigned)(d_ & 511) << 17);
        }
        while (true) {
            if (t == 0) anyPend = 0;
            __syncthreads();
            if (pending) {
                int pos = atomicAdd(&lcnt[b], 1);
                if (pos < 16) { stg[b][pos] = val; pending = false; }
                else anyPend = 1;
            }
            __syncthreads();
            int ap = anyPend;
            if (lcnt[t] >= 16) {
                int gp = atomicAdd(&gcur[t], 16);
                uint4* dp = (uint4*)&tmp[gp];
                const uint4* sp = (const uint4*)stg[t];
                dp[0] = sp[0]; dp[1] = sp[1]; dp[2] = sp[2]; dp[3] = sp[3];
                lcnt[t] = 0;
            }
            if (!ap) break;
            __syncthreads();   // order flush writes vs next round's inserts
        }
        __syncthreads();       // order flush (lcnt reset) vs next outer inserts
    }
    // final partial flush: claim 16, pad with sentinels (keeps alignment)
    int c = lcnt[t];
    if (t < NB && c > 0) {
        int gp = atomicAdd(&gcur[t], 16);
        for (int i = 0; i < 16; i++)
            tmp[gp + i] = (i < c) ? stg[t][i] : 0xFFFFFFFFu;
    }
}

// ---------------- Pass C: per-bucket CSR finalize ----------------
__global__ __launch_bounds__(256) void k_csr(const int* __restrict__ bbase,
    const int* __restrict__ gcur, const int* __restrict__ rowptr,
    const unsigned* __restrict__ tmp, int* __restrict__ srcIdx, int N)
{
    __shared__ int lcur[512];
    int b = blockIdx.x, t = threadIdx.x;
    int nb = b << 9;
    for (int i = t; i < 512; i += 256) {
        int n = nb + i;
        lcur[i] = (n < N) ? rowptr[n] : 0;
    }
    __syncthreads();
    int beg = bbase[b], end = gcur[b];
    for (int e = beg + t; e < end; e += 256) {
        unsigned v = tmp[e];
        if (v == 0xFFFFFFFFu) continue;
        int dl = v >> 17;
        int s  = v & 0x1FFFF;
        int pos = atomicAdd(&lcur[dl], 1);
        srcIdx[pos] = s;
    }
}

// ---------------- W prep: transpose + bf16 split + XOR-swizzle ----------------
template<int DOUT>
__global__ __launch_bounds__(256) void k_prepW(const float* __restrict__ W,
    unsigned short* __restrict__ Wh, unsigned short* __restrict__ Wl)
{
    int idx = blockIdx.x * 256 + threadIdx.x;
    if (idx >= 128 * DOUT) return;
    int c = idx % DOUT;
    int k = idx / DOUT;
    float w = W[idx];
    unsigned short hi = f2bf(w);
    unsigned short lo = f2bf(w - bf2f(hi));
    int boff = c * 256 + ((2 * k) ^ ((c & 7) << 4));
    *(unsigned short*)((char*)Wh + boff) = hi;
    *(unsigned short*)((char*)Wl + boff) = lo;
}

// ---------------- MFMA GEMM: out[n][:] = f(in[n][:]) @ W  (DIN=128) ----------------
template<int DOUT, int MODE>
__global__ __launch_bounds__(256) void k_gemm_mfma(
    const float* __restrict__ in,
    const unsigned short* __restrict__ Wth, const unsigned short* __restrict__ Wtl,
    const float* __restrict__ bprev,
    const float* __restrict__ ns, const float* __restrict__ nd,
    float* __restrict__ out, int N)
{
    constexpr int NT = DOUT / 16;
    __shared__ __align__(16) unsigned short Wh[DOUT * 128];
    __shared__ __align__(16) unsigned short Wl[DOUT * 128];

    const int t = threadIdx.x;
    const int w = t >> 6, l = t & 63;

#pragma unroll
    for (int i = 0; i < DOUT * 256 / 4096; i++) {
        int off = i * 4096 + t * 16;
        *(float4*)((char*)Wh + off) = *(const float4*)((const char*)Wth + off);
        *(float4*)((char*)Wl + off) = *(const float4*)((const char*)Wtl + off);
    }

    const int rl   = l & 15;
    const int kgrp = l >> 4;
    const int row  = blockIdx.x * 64 + w * 16 + rl;
    const int rowc = row < N ? row : N - 1;
    const float* arow = in + (size_t)rowc * 128;

    float av[4][8];
#pragma unroll
    for (int ks = 0; ks < 4; ks++) {
        int kb = ks * 32 + kgrp * 8;
        float4 v0 = *(const float4*)(arow + kb);
        float4 v1 = *(const float4*)(arow + kb + 4);
        av[ks][0] = v0.x; av[ks][1] = v0.y; av[ks][2] = v0.z; av[ks][3] = v0.w;
        av[ks][4] = v1.x; av[ks][5] = v1.y; av[ks][6] = v1.z; av[ks][7] = v1.w;
    }
    if (MODE == 1) {
        float ndv = nd[rowc], nsv = ns[rowc];
#pragma unroll
        for (int ks = 0; ks < 4; ks++) {
            int kb = ks * 32 + kgrp * 8;
            float4 b0 = *(const float4*)(bprev + kb);
            float4 b1 = *(const float4*)(bprev + kb + 4);
            float bb[8] = {b0.x, b0.y, b0.z, b0.w, b1.x, b1.y, b1.z, b1.w};
#pragma unroll
            for (int j = 0; j < 8; j++)
                av[ks][j] = fmaxf(av[ks][j] * ndv + bb[j], 0.f) * nsv;
        }
    } else {
        float nsv = ns[rowc];
#pragma unroll
        for (int ks = 0; ks < 4; ks++)
#pragma unroll
            for (int j = 0; j < 8; j++)
                av[ks][j] *= nsv;
    }
    short8 Ah[4], Al[4];
#pragma unroll
    for (int ks = 0; ks < 4; ks++)
#pragma unroll
        for (int j = 0; j < 8; j++) {
            unsigned short hi = f2bf(av[ks][j]);
            Ah[ks][j] = (short)hi;
            Al[ks][j] = (short)f2bf(av[ks][j] - bf2f(hi));
        }

    __syncthreads();

    f32x4 acc[NT];
#pragma unroll
    for (int tt = 0; tt < NT; tt++) acc[tt] = (f32x4){0.f, 0.f, 0.f, 0.f};

#pragma unroll
    for (int ks = 0; ks < 4; ks++) {
        int kbyte = ks * 64 + kgrp * 16;
#pragma unroll
        for (int tt = 0; tt < NT; tt++) {
            int c = tt * 16 + rl;
            int boff = c * 256 + (kbyte ^ ((c & 7) << 4));
            short8 Bh = *(short8*)((char*)Wh + boff);
            short8 Bl = *(short8*)((char*)Wl + boff);
            acc[tt] = __builtin_amdgcn_mfma_f32_16x16x32_bf16(Ah[ks], Bh, acc[tt], 0, 0, 0);
            acc[tt] = __builtin_amdgcn_mfma_f32_16x16x32_bf16(Al[ks], Bh, acc[tt], 0, 0, 0);
            acc[tt] = __builtin_amdgcn_mfma_f32_16x16x32_bf16(Ah[ks], Bl, acc[tt], 0, 0, 0);
        }
    }

    const int orow = blockIdx.x * 64 + w * 16 + kgrp * 4;
#pragma unroll
    for (int r = 0; r < 4; r++) {
        if (orow + r < N) {
#pragma unroll
            for (int tt = 0; tt < NT; tt++)
                out[(size_t)(orow + r) * DOUT + tt * 16 + rl] = acc[tt][r];
        }
    }
}

// ---------------- pull-based aggregation ----------------
template<int D, int FINAL>
__global__ __launch_bounds__(256) void k_agg(
    const int* __restrict__ rowptr, const int* __restrict__ cnt,
    const int* __restrict__ srcIdx, const float* __restrict__ h,
    const float* __restrict__ nd, const float* __restrict__ b3,
    float* __restrict__ m, int N)
{
    constexpr int TPN = D / 4;
    constexpr int NPB = 256 / TPN;
    int t = threadIdx.x;
    int node = blockIdx.x * NPB + t / TPN;
    if (node >= N) return;
    int c = (t % TPN) * 4;

    int beg = rowptr[node];
    int end = beg + cnt[node];
    float4 acc = make_float4(0.f, 0.f, 0.f, 0.f);
    for (int e = beg; e < end; e++) {
        int s = srcIdx[e];
        float4 v = *(const float4*)&h[(size_t)s * D + c];
        acc.x += v.x; acc.y += v.y; acc.z += v.z; acc.w += v.w;
    }
    if (FINAL) {
        float ndv = nd[node];
        acc.x = acc.x * ndv + b3[c + 0];
        acc.y = acc.y * ndv + b3[c + 1];
        acc.z = acc.z * ndv + b3[c + 2];
        acc.w = acc.w * ndv + b3[c + 3];
    }
    *(float4*)&m[(size_t)node * D + c] = acc;
}

extern "C" void kernel_launch(void* const* d_in, const int* in_sizes, int n_in,
                              void* d_out, int out_size, void* d_ws, size_t ws_size,
                              hipStream_t stream) {
    const float* x  = (const float*)d_in[0];
    const int*   src = (const int*)d_in[1];
    const int*   dst = (const int*)d_in[2];
    const float* W1 = (const float*)d_in[3];
    const float* b1 = (const float*)d_in[4];
    const float* W2 = (const float*)d_in[5];
    const float* b2 = (const float*)d_in[6];
    const float* W3 = (const float*)d_in[7];
    const float* b3 = (const float*)d_in[8];
    float* out = (float*)d_out;

    const int N = NN;
    const int E = in_sizes[1];
    const int G = (N + 255) / 256;

    char* ws = (char*)d_ws;
    float* bufA  = (float*)ws;                                  // N*128 f32
    float* bufB  = (float*)(ws + (size_t)N * 128 * 4);          // N*128 f32
    char*  p     = ws + (size_t)N * 128 * 4 * 2;
    float* ns    = (float*)p;              p += (size_t)N * 4;
    float* nd    = (float*)p;              p += (size_t)N * 4;
    int*   degO  = (int*)p;                p += (size_t)N * 4;
    int*   degI  = (int*)p;                p += (size_t)N * 4;
    int*   rowp  = (int*)p;                p += (size_t)N * 4;
    int*   part  = (int*)p;                p += (size_t)512 * 4;
    int*   srcIdx= (int*)p;                p += (size_t)E * 4;
    unsigned short* W1h = (unsigned short*)p; p += 128 * 128 * 2;
    unsigned short* W1l = (unsigned short*)p; p += 128 * 128 * 2;
    unsigned short* W2h = (unsigned short*)p; p += 128 * 128 * 2;
    unsigned short* W2l = (unsigned short*)p; p += 128 * 128 * 2;
    unsigned short* W3h = (unsigned short*)p; p += 64 * 128 * 2;
    unsigned short* W3l = (unsigned short*)p; p += 64 * 128 * 2;
    int* bcnt  = (int*)p;                  p += 256 * 4;
    int* bbase = (int*)p;                  p += 256 * 4;
    int* gcur  = (int*)p;                  p += 256 * 4;
    unsigned* tmp = (unsigned*)p;          p += (size_t)(E + NB * (16 + 16 * PB_BLOCKS)) * 4;

    // W prep (independent)
    k_prepW<128><<<64, 256, 0, stream>>>(W1, W1h, W1l);
    k_prepW<128><<<64, 256, 0, stream>>>(W2, W2h, W2l);
    k_prepW<64><<<32, 256, 0, stream>>>(W3, W3h, W3l);

    // degrees + norms
    hipMemsetAsync(degO, 0, (size_t)2 * N * 4, stream);
    k_deg<<<(E + 255) / 256, 256, 0, stream>>>(src, dst, degO, degI, E);
    k_norm<<<G, 256, 0, stream>>>(degO, degI, ns, nd, N);

    // rowptr = exclusive scan of degI
    k_scan1<<<G, 256, 0, stream>>>(degI, part, N);
    k_scan2<<<1, 512, 0, stream>>>(part, G);
    k_scan3<<<G, 256, 0, stream>>>(degI, part, rowp, N);

    // bucketed CSR build
    k_bhist<<<NB, 256, 0, stream>>>(degI, bcnt, N);
    k_bscan<<<1, 256, 0, stream>>>(bcnt, bbase, gcur);
    k_bscatter<<<PB_BLOCKS, 256, 0, stream>>>(src, dst, gcur, tmp, E);
    k_csr<<<NB, 256, 0, stream>>>(bbase, gcur, rowp, tmp, srcIdx, N);

    const int gemm_grid = (N + 63) / 64;
    const int agg128 = (N + 7) / 8;
    const int agg64  = (N + 15) / 16;

    // ---- layer 1 ----
    k_gemm_mfma<128, 0><<<gemm_grid, 256, 0, stream>>>(x, W1h, W1l, nullptr, ns, nd, bufA, N);
    k_agg<128, 0><<<agg128, 256, 0, stream>>>(rowp, degI, srcIdx, bufA, nd, b3, bufB, N);

    // ---- layer 2 ----
    k_gemm_mfma<128, 1><<<gemm_grid, 256, 0, stream>>>(bufB, W2h, W2l, b1, ns, nd, bufA, N);
    k_agg<128, 0><<<agg128, 256, 0, stream>>>(rowp, degI, srcIdx, bufA, nd, b3, bufB, N);

    // ---- layer 3 (final epilogue fused) ----
    k_gemm_mfma<64, 1><<<gemm_grid, 256, 0, stream>>>(bufB, W3h, W3l, b2, ns, nd, bufA, N);
    k_agg<64, 1><<<agg64, 256, 0, stream>>>(rowp, degI, srcIdx, bufA, nd, b3, out, N);
}

// Round 5
// 536.546 us; speedup vs baseline: 13.0487x; 1.1774x over previous
//
#include <hip/hip_runtime.h>

#define NN 100000
#define NB 196            // ceil(NN / 512) buckets of 512 nodes
#define PB_BLOCKS 192     // blocks in k_bscatter2

typedef short short8 __attribute__((ext_vector_type(8)));
typedef float f32x4 __attribute__((ext_vector_type(4)));

__device__ inline unsigned short f2bf(float x) {
    unsigned u = __float_as_uint(x);
    unsigned r = (u + 0x7FFF + ((u >> 16) & 1)) >> 16;
    return (unsigned short)r;
}
__device__ inline float bf2f(unsigned short h) {
    return __uint_as_float(((unsigned)h) << 16);
}

// ---------------- bucket histograms (src & dst) via LDS ----------------
__global__ __launch_bounds__(256) void k_bhist2(const int* __restrict__ src,
    const int* __restrict__ dst, int* __restrict__ bcntS, int* __restrict__ bcntD, int E)
{
    __shared__ int hs[NB], hd[NB];
    int t = threadIdx.x;
    if (t < NB) { hs[t] = 0; hd[t] = 0; }
    __syncthreads();
    int stride = gridDim.x * 256;
    for (int e = blockIdx.x * 256 + t; e < E; e += stride) {
        atomicAdd(&hs[src[e] >> 9], 1);
        atomicAdd(&hd[dst[e] >> 9], 1);
    }
    __syncthreads();
    if (t < NB) {
        if (hs[t]) atomicAdd(&bcntS[t], hs[t]);
        if (hd[t]) atomicAdd(&bcntD[t], hd[t]);
    }
}

// ---------------- bucket scans: padded bases for tmpD/tmpS + true edge base ----------------
__global__ __launch_bounds__(256) void k_bscan2(const int* __restrict__ bcntS,
    const int* __restrict__ bcntD, int* __restrict__ bbaseS, int* __restrict__ gcurS,
    int* __restrict__ bbaseD, int* __restrict__ gcurD, int* __restrict__ ebase)
{
    __shared__ int s[256];
    int t = threadIdx.x;
    int cD = (t < NB) ? bcntD[t] : 0;
    int cS = (t < NB) ? bcntS[t] : 0;

    // scan 1: padded D sizes
    int v = ((cD + 15) & ~15) + 16 * PB_BLOCKS;
    if (t >= NB) v = 0;
    s[t] = v;
    __syncthreads();
#pragma unroll
    for (int off = 1; off < 256; off <<= 1) {
        int x = (t >= off) ? s[t - off] : 0;
        __syncthreads(); s[t] += x; __syncthreads();
    }
    if (t < NB) { int e = s[t] - v; bbaseD[t] = e; gcurD[t] = e; }
    __syncthreads();

    // scan 2: padded S sizes
    v = ((cS + 15) & ~15) + 16 * PB_BLOCKS;
    if (t >= NB) v = 0;
    s[t] = v;
    __syncthreads();
#pragma unroll
    for (int off = 1; off < 256; off <<= 1) {
        int x = (t >= off) ? s[t - off] : 0;
        __syncthreads(); s[t] += x; __syncthreads();
    }
    if (t < NB) { int e = s[t] - v; bbaseS[t] = e; gcurS[t] = e; }
    __syncthreads();

    // scan 3: true D counts -> global edge base per bucket
    v = (t < NB) ? cD : 0;
    s[t] = v;
    __syncthreads();
#pragma unroll
    for (int off = 1; off < 256; off <<= 1) {
        int x = (t >= off) ? s[t - off] : 0;
        __syncthreads(); s[t] += x; __syncthreads();
    }
    if (t < NB) ebase[t] = s[t] - v;
}

// ---------------- dual-stream LDS-staged bucket scatter (full-line writes) ----------------
__global__ __launch_bounds__(256) void k_bscatter2(const int* __restrict__ src,
    const int* __restrict__ dst, int* __restrict__ gcurD, int* __restrict__ gcurS,
    unsigned* __restrict__ tmpD, unsigned* __restrict__ tmpS, int E)
{
    __shared__ unsigned stgD[256][16];
    __shared__ unsigned stgS[256][16];
    __shared__ int lcntD[256], lcntS[256];
    __shared__ int anyPend;
    int t = threadIdx.x;
    lcntD[t] = 0; lcntS[t] = 0;

    int chunk = (E + PB_BLOCKS - 1) / PB_BLOCKS;
    int e0 = blockIdx.x * chunk;
    int e1 = min(E, e0 + chunk);

    for (int base = e0; base < e1; base += 256) {
        int e = base + t;
        bool pD = e < e1, pS = pD;
        unsigned vD = 0, vS = 0; int bD = 0, bS = 0;
        if (pD) {
            int s_ = src[e], d_ = dst[e];
            bD = d_ >> 9; vD = (unsigned)s_ | ((unsigned)(d_ & 511) << 17);
            bS = s_ >> 9; vS = (unsigned)(s_ & 511);
        }
        while (true) {
            if (t == 0) anyPend = 0;
            __syncthreads();
            if (pD) {
                int pos = atomicAdd(&lcntD[bD], 1);
                if (pos < 16) { stgD[bD][pos] = vD; pD = false; } else anyPend = 1;
            }
            if (pS) {
                int pos = atomicAdd(&lcntS[bS], 1);
                if (pos < 16) { stgS[bS][pos] = vS; pS = false; } else anyPend = 1;
            }
            __syncthreads();
            int ap = anyPend;
            if (lcntD[t] >= 16) {
                int gp = atomicAdd(&gcurD[t], 16);
                uint4* dp = (uint4*)&tmpD[gp];
                const uint4* sp = (const uint4*)stgD[t];
                dp[0] = sp[0]; dp[1] = sp[1]; dp[2] = sp[2]; dp[3] = sp[3];
                lcntD[t] = 0;
            }
            if (lcntS[t] >= 16) {
                int gp = atomicAdd(&gcurS[t], 16);
                uint4* dp = (uint4*)&tmpS[gp];
                const uint4* sp = (const uint4*)stgS[t];
                dp[0] = sp[0]; dp[1] = sp[1]; dp[2] = sp[2]; dp[3] = sp[3];
                lcntS[t] = 0;
            }
            if (!ap) break;
            __syncthreads();
        }
        __syncthreads();
    }
    int cD = lcntD[t];
    if (t < NB && cD > 0) {
        int gp = atomicAdd(&gcurD[t], 16);
        for (int i = 0; i < 16; i++) tmpD[gp + i] = (i < cD) ? stgD[t][i] : 0xFFFFFFFFu;
    }
    int cS = lcntS[t];
    if (t < NB && cS > 0) {
        int gp = atomicAdd(&gcurS[t], 16);
        for (int i = 0; i < 16; i++) tmpS[gp + i] = (i < cS) ? stgS[t][i] : 0xFFFFFFFFu;
    }
}

// ---------------- src-bucket count -> ns ----------------
__global__ __launch_bounds__(256) void k_cntS(const int* __restrict__ bbaseS,
    const int* __restrict__ gcurS, const unsigned* __restrict__ tmpS,
    float* __restrict__ ns, int N)
{
    __shared__ int cnt[512];
    int b = blockIdx.x, t = threadIdx.x;
    cnt[t] = 0; cnt[t + 256] = 0;
    __syncthreads();
    int beg = bbaseS[b], end = gcurS[b];
    for (int e = beg + t; e < end; e += 256) {
        unsigned v = tmpS[e];
        if (v != 0xFFFFFFFFu) atomicAdd(&cnt[v], 1);
    }
    __syncthreads();
    int nb = b << 9;
    for (int i = t; i < 512; i += 256) {
        int n = nb + i;
        if (n < N) ns[n] = rsqrtf(fmaxf((float)cnt[i], 1.0f));
    }
}

// ---------------- dst-bucket: degI + nd + rowptr (LDS scan) + CSR fill ----------------
__global__ __launch_bounds__(256) void k_csrD(const int* __restrict__ bbaseD,
    const int* __restrict__ gcurD, const int* __restrict__ ebase,
    const unsigned* __restrict__ tmpD, int* __restrict__ degI, float* __restrict__ nd,
    int* __restrict__ rowptr, int* __restrict__ srcIdx, int N)
{
    __shared__ int cnt[512];
    __shared__ int sblk[256];
    __shared__ int lcur[512];
    int b = blockIdx.x, t = threadIdx.x;
    cnt[t] = 0; cnt[t + 256] = 0;
    __syncthreads();
    int beg = bbaseD[b], end = gcurD[b];
    for (int e = beg + t; e < end; e += 256) {
        unsigned v = tmpD[e];
        if (v != 0xFFFFFFFFu) atomicAdd(&cnt[v >> 17], 1);
    }
    __syncthreads();
    int v0 = cnt[2 * t], v1 = cnt[2 * t + 1];
    sblk[t] = v0 + v1;
    __syncthreads();
#pragma unroll
    for (int off = 1; off < 256; off <<= 1) {
        int x = (t >= off) ? sblk[t - off] : 0;
        __syncthreads(); sblk[t] += x; __syncthreads();
    }
    int S = sblk[t];
    int eb = ebase[b];
    int e0 = eb + S - v0 - v1;
    int e1_ = e0 + v0;
    int nb = b << 9;
    int n0 = nb + 2 * t, n1 = n0 + 1;
    if (n0 < N) { rowptr[n0] = e0;  degI[n0] = v0; nd[n0] = rsqrtf(fmaxf((float)v0, 1.f)); }
    if (n1 < N) { rowptr[n1] = e1_; degI[n1] = v1; nd[n1] = rsqrtf(fmaxf((float)v1, 1.f)); }
    lcur[2 * t] = e0; lcur[2 * t + 1] = e1_;
    __syncthreads();
    for (int e = beg + t; e < end; e += 256) {
        unsigned v = tmpD[e];
        if (v == 0xFFFFFFFFu) continue;
        int pos = atomicAdd(&lcur[v >> 17], 1);
        srcIdx[pos] = (int)(v & 0x1FFFFu);
    }
}

// ---------------- W prep: transpose + bf16 split + XOR-swizzle ----------------
template<int DOUT>
__global__ __launch_bounds__(256) void k_prepW(const float* __restrict__ W,
    unsigned short* __restrict__ Wh, unsigned short* __restrict__ Wl)
{
    int idx = blockIdx.x * 256 + threadIdx.x;
    if (idx >= 128 * DOUT) return;
    int c = idx % DOUT;
    int k = idx / DOUT;
    float w = W[idx];
    unsigned short hi = f2bf(w);
    unsigned short lo = f2bf(w - bf2f(hi));
    int boff = c * 256 + ((2 * k) ^ ((c & 7) << 4));
    *(unsigned short*)((char*)Wh + boff) = hi;
    *(unsigned short*)((char*)Wl + boff) = lo;
}

// ---------------- MFMA GEMM: out[n][:] = f(in[n][:]) @ W  (DIN=128) ----------------
template<int DOUT, int MODE>
__global__ __launch_bounds__(256) void k_gemm_mfma(
    const float* __restrict__ in,
    const unsigned short* __restrict__ Wth, const unsigned short* __restrict__ Wtl,
    const float* __restrict__ bprev,
    const float* __restrict__ ns, const float* __restrict__ nd,
    float* __restrict__ out, int N)
{
    constexpr int NT = DOUT / 16;
    __shared__ __align__(16) unsigned short Wh[DOUT * 128];
    __shared__ __align__(16) unsigned short Wl[DOUT * 128];

    const int t = threadIdx.x;
    const int w = t >> 6, l = t & 63;

#pragma unroll
    for (int i = 0; i < DOUT * 256 / 4096; i++) {
        int off = i * 4096 + t * 16;
        *(float4*)((char*)Wh + off) = *(const float4*)((const char*)Wth + off);
        *(float4*)((char*)Wl + off) = *(const float4*)((const char*)Wtl + off);
    }

    const int rl   = l & 15;
    const int kgrp = l >> 4;
    const int row  = blockIdx.x * 64 + w * 16 + rl;
    const int rowc = row < N ? row : N - 1;
    const float* arow = in + (size_t)rowc * 128;

    float av[4][8];
#pragma unroll
    for (int ks = 0; ks < 4; ks++) {
        int kb = ks * 32 + kgrp * 8;
        float4 v0 = *(const float4*)(arow + kb);
        float4 v1 = *(const float4*)(arow + kb + 4);
        av[ks][0] = v0.x; av[ks][1] = v0.y; av[ks][2] = v0.z; av[ks][3] = v0.w;
        av[ks][4] = v1.x; av[ks][5] = v1.y; av[ks][6] = v1.z; av[ks][7] = v1.w;
    }
    if (MODE == 1) {
        float ndv = nd[rowc], nsv = ns[rowc];
#pragma unroll
        for (int ks = 0; ks < 4; ks++) {
            int kb = ks * 32 + kgrp * 8;
            float4 b0 = *(const float4*)(bprev + kb);
            float4 b1 = *(const float4*)(bprev + kb + 4);
            float bb[8] = {b0.x, b0.y, b0.z, b0.w, b1.x, b1.y, b1.z, b1.w};
#pragma unroll
            for (int j = 0; j < 8; j++)
                av[ks][j] = fmaxf(av[ks][j] * ndv + bb[j], 0.f) * nsv;
        }
    } else {
        float nsv = ns[rowc];
#pragma unroll
        for (int ks = 0; ks < 4; ks++)
#pragma unroll
            for (int j = 0; j < 8; j++)
                av[ks][j] *= nsv;
    }
    short8 Ah[4], Al[4];
#pragma unroll
    for (int ks = 0; ks < 4; ks++)
#pragma unroll
        for (int j = 0; j < 8; j++) {
            unsigned short hi = f2bf(av[ks][j]);
            Ah[ks][j] = (short)hi;
            Al[ks][j] = (short)f2bf(av[ks][j] - bf2f(hi));
        }

    __syncthreads();

    f32x4 acc[NT];
#pragma unroll
    for (int tt = 0; tt < NT; tt++) acc[tt] = (f32x4){0.f, 0.f, 0.f, 0.f};

#pragma unroll
    for (int ks = 0; ks < 4; ks++) {
        int kbyte = ks * 64 + kgrp * 16;
#pragma unroll
        for (int tt = 0; tt < NT; tt++) {
            int c = tt * 16 + rl;
            int boff = c * 256 + (kbyte ^ ((c & 7) << 4));
            short8 Bh = *(short8*)((char*)Wh + boff);
            short8 Bl = *(short8*)((char*)Wl + boff);
            acc[tt] = __builtin_amdgcn_mfma_f32_16x16x32_bf16(Ah[ks], Bh, acc[tt], 0, 0, 0);
            acc[tt] = __builtin_amdgcn_mfma_f32_16x16x32_bf16(Al[ks], Bh, acc[tt], 0, 0, 0);
            acc[tt] = __builtin_amdgcn_mfma_f32_16x16x32_bf16(Ah[ks], Bl, acc[tt], 0, 0, 0);
        }
    }

    const int orow = blockIdx.x * 64 + w * 16 + kgrp * 4;
#pragma unroll
    for (int r = 0; r < 4; r++) {
        if (orow + r < N) {
#pragma unroll
            for (int tt = 0; tt < NT; tt++)
                out[(size_t)(orow + r) * DOUT + tt * 16 + rl] = acc[tt][r];
        }
    }
}

// ---------------- pull-based aggregation ----------------
template<int D, int FINAL>
__global__ __launch_bounds__(256) void k_agg(
    const int* __restrict__ rowptr, const int* __restrict__ cnt,
    const int* __restrict__ srcIdx, const float* __restrict__ h,
    const float* __restrict__ nd, const float* __restrict__ b3,
    float* __restrict__ m, int N)
{
    constexpr int TPN = D / 4;
    constexpr int NPB = 256 / TPN;
    int t = threadIdx.x;
    int node = blockIdx.x * NPB + t / TPN;
    if (node >= N) return;
    int c = (t % TPN) * 4;

    int beg = rowptr[node];
    int end = beg + cnt[node];
    float4 acc = make_float4(0.f, 0.f, 0.f, 0.f);
    for (int e = beg; e < end; e++) {
        int s = srcIdx[e];
        float4 v = *(const float4*)&h[(size_t)s * D + c];
        acc.x += v.x; acc.y += v.y; acc.z += v.z; acc.w += v.w;
    }
    if (FINAL) {
        float ndv = nd[node];
        acc.x = acc.x * ndv + b3[c + 0];
        acc.y = acc.y * ndv + b3[c + 1];
        acc.z = acc.z * ndv + b3[c + 2];
        acc.w = acc.w * ndv + b3[c + 3];
    }
    *(float4*)&m[(size_t)node * D + c] = acc;
}

extern "C" void kernel_launch(void* const* d_in, const int* in_sizes, int n_in,
                              void* d_out, int out_size, void* d_ws, size_t ws_size,
                              hipStream_t stream) {
    const float* x  = (const float*)d_in[0];
    const int*   src = (const int*)d_in[1];
    const int*   dst = (const int*)d_in[2];
    const float* W1 = (const float*)d_in[3];
    const float* b1 = (const float*)d_in[4];
    const float* W2 = (const float*)d_in[5];
    const float* b2 = (const float*)d_in[6];
    const float* W3 = (const float*)d_in[7];
    const float* b3 = (const float*)d_in[8];
    float* out = (float*)d_out;

    const int N = NN;
    const int E = in_sizes[1];

    char* ws = (char*)d_ws;
    float* bufA  = (float*)ws;                                  // N*128 f32 (aliases tmpD)
    float* bufB  = (float*)(ws + (size_t)N * 128 * 4);          // N*128 f32 (aliases tmpS)
    unsigned* tmpD = (unsigned*)bufA;                           // consumed before gemm1 writes bufA
    unsigned* tmpS = (unsigned*)bufB;                           // consumed before agg1 writes bufB
    char*  p     = ws + (size_t)N * 128 * 4 * 2;
    float* ns    = (float*)p;              p += (size_t)N * 4;
    float* nd    = (float*)p;              p += (size_t)N * 4;
    int*   degI  = (int*)p;                p += (size_t)N * 4;
    int*   rowp  = (int*)p;                p += (size_t)N * 4;
    int*   srcIdx= (int*)p;                p += (size_t)E * 4;
    unsigned short* W1h = (unsigned short*)p; p += 128 * 128 * 2;
    unsigned short* W1l = (unsigned short*)p; p += 128 * 128 * 2;
    unsigned short* W2h = (unsigned short*)p; p += 128 * 128 * 2;
    unsigned short* W2l = (unsigned short*)p; p += 128 * 128 * 2;
    unsigned short* W3h = (unsigned short*)p; p += 64 * 128 * 2;
    unsigned short* W3l = (unsigned short*)p; p += 64 * 128 * 2;
    int* bcntS = (int*)p;                  p += 256 * 4;
    int* bcntD = (int*)p;                  p += 256 * 4;
    int* bbaseS= (int*)p;                  p += 256 * 4;
    int* bbaseD= (int*)p;                  p += 256 * 4;
    int* gcurS = (int*)p;                  p += 256 * 4;
    int* gcurD = (int*)p;                  p += 256 * 4;
    int* ebase = (int*)p;                  p += 256 * 4;

    // W prep (independent)
    k_prepW<128><<<64, 256, 0, stream>>>(W1, W1h, W1l);
    k_prepW<128><<<64, 256, 0, stream>>>(W2, W2h, W2l);
    k_prepW<64><<<32, 256, 0, stream>>>(W3, W3h, W3l);

    // bucketed degree/CSR pipeline (no per-edge global atomics)
    hipMemsetAsync(bcntS, 0, 2 * 256 * 4, stream);
    k_bhist2<<<192, 256, 0, stream>>>(src, dst, bcntS, bcntD, E);
    k_bscan2<<<1, 256, 0, stream>>>(bcntS, bcntD, bbaseS, gcurS, bbaseD, gcurD, ebase);
    k_bscatter2<<<PB_BLOCKS, 256, 0, stream>>>(src, dst, gcurD, gcurS, tmpD, tmpS, E);
    k_cntS<<<NB, 256, 0, stream>>>(bbaseS, gcurS, tmpS, ns, N);
    k_csrD<<<NB, 256, 0, stream>>>(bbaseD, gcurD, ebase, tmpD, degI, nd, rowp, srcIdx, N);

    const int gemm_grid = (N + 63) / 64;
    const int agg128 = (N + 7) / 8;
    const int agg64  = (N + 15) / 16;

    // ---- layer 1 ----
    k_gemm_mfma<128, 0><<<gemm_grid, 256, 0, stream>>>(x, W1h, W1l, nullptr, ns, nd, bufA, N);
    k_agg<128, 0><<<agg128, 256, 0, stream>>>(rowp, degI, srcIdx, bufA, nd, b3, bufB, N);

    // ---- layer 2 ----
    k_gemm_mfma<128, 1><<<gemm_grid, 256, 0, stream>>>(bufB, W2h, W2l, b1, ns, nd, bufA, N);
    k_agg<128, 0><<<agg128, 256, 0, stream>>>(rowp, degI, srcIdx, bufA, nd, b3, bufB, N);

    // ---- layer 3 (final epilogue fused) ----
    k_gemm_mfma<64, 1><<<gemm_grid, 256, 0, stream>>>(bufB, W3h, W3l, b2, ns, nd, bufA, N);
    k_agg<64, 1><<<agg64, 256, 0, stream>>>(rowp, degI, srcIdx, bufA, nd, b3, out, N);
}

// Round 6
// 413.142 us; speedup vs baseline: 16.9464x; 1.2987x over previous
//
#include <hip/hip_runtime.h>

#define NN 100000
#define NB 196            // ceil(NN / 512) buckets of 512 nodes
#define PB_BLOCKS 192     // blocks in k_bscatter2

typedef short short8 __attribute__((ext_vector_type(8)));
typedef unsigned short u16x8 __attribute__((ext_vector_type(8)));
typedef float f32x4 __attribute__((ext_vector_type(4)));

__device__ inline unsigned short f2bf(float x) {
    unsigned u = __float_as_uint(x);
    unsigned r = (u + 0x7FFF + ((u >> 16) & 1)) >> 16;
    return (unsigned short)r;
}
__device__ inline float bf2f(unsigned short h) {
    return __uint_as_float(((unsigned)h) << 16);
}

// ---------------- bucket histograms (src & dst) via LDS ----------------
__global__ __launch_bounds__(256) void k_bhist2(const int* __restrict__ src,
    const int* __restrict__ dst, int* __restrict__ bcntS, int* __restrict__ bcntD, int E)
{
    __shared__ int hs[NB], hd[NB];
    int t = threadIdx.x;
    if (t < NB) { hs[t] = 0; hd[t] = 0; }
    __syncthreads();
    int stride = gridDim.x * 256;
    for (int e = blockIdx.x * 256 + t; e < E; e += stride) {
        atomicAdd(&hs[src[e] >> 9], 1);
        atomicAdd(&hd[dst[e] >> 9], 1);
    }
    __syncthreads();
    if (t < NB) {
        if (hs[t]) atomicAdd(&bcntS[t], hs[t]);
        if (hd[t]) atomicAdd(&bcntD[t], hd[t]);
    }
}

// ---------------- bucket scans: padded bases for tmpD/tmpS + true edge base ----------------
__global__ __launch_bounds__(256) void k_bscan2(const int* __restrict__ bcntS,
    const int* __restrict__ bcntD, int* __restrict__ bbaseS, int* __restrict__ gcurS,
    int* __restrict__ bbaseD, int* __restrict__ gcurD, int* __restrict__ ebase)
{
    __shared__ int s[256];
    int t = threadIdx.x;
    int cD = (t < NB) ? bcntD[t] : 0;
    int cS = (t < NB) ? bcntS[t] : 0;

    int v = ((cD + 15) & ~15) + 16 * PB_BLOCKS;
    if (t >= NB) v = 0;
    s[t] = v;
    __syncthreads();
#pragma unroll
    for (int off = 1; off < 256; off <<= 1) {
        int x = (t >= off) ? s[t - off] : 0;
        __syncthreads(); s[t] += x; __syncthreads();
    }
    if (t < NB) { int e = s[t] - v; bbaseD[t] = e; gcurD[t] = e; }
    __syncthreads();

    v = ((cS + 15) & ~15) + 16 * PB_BLOCKS;
    if (t >= NB) v = 0;
    s[t] = v;
    __syncthreads();
#pragma unroll
    for (int off = 1; off < 256; off <<= 1) {
        int x = (t >= off) ? s[t - off] : 0;
        __syncthreads(); s[t] += x; __syncthreads();
    }
    if (t < NB) { int e = s[t] - v; bbaseS[t] = e; gcurS[t] = e; }
    __syncthreads();

    v = (t < NB) ? cD : 0;
    s[t] = v;
    __syncthreads();
#pragma unroll
    for (int off = 1; off < 256; off <<= 1) {
        int x = (t >= off) ? s[t - off] : 0;
        __syncthreads(); s[t] += x; __syncthreads();
    }
    if (t < NB) ebase[t] = s[t] - v;
}

// ---------------- dual-stream LDS-staged bucket scatter (full-line writes) ----------------
__global__ __launch_bounds__(256) void k_bscatter2(const int* __restrict__ src,
    const int* __restrict__ dst, int* __restrict__ gcurD, int* __restrict__ gcurS,
    unsigned* __restrict__ tmpD, unsigned* __restrict__ tmpS, int E)
{
    __shared__ unsigned stgD[256][16];
    __shared__ unsigned stgS[256][16];
    __shared__ int lcntD[256], lcntS[256];
    __shared__ int anyPend;
    int t = threadIdx.x;
    lcntD[t] = 0; lcntS[t] = 0;

    int chunk = (E + PB_BLOCKS - 1) / PB_BLOCKS;
    int e0 = blockIdx.x * chunk;
    int e1 = min(E, e0 + chunk);

    for (int base = e0; base < e1; base += 256) {
        int e = base + t;
        bool pD = e < e1, pS = pD;
        unsigned vD = 0, vS = 0; int bD = 0, bS = 0;
        if (pD) {
            int s_ = src[e], d_ = dst[e];
            bD = d_ >> 9; vD = (unsigned)s_ | ((unsigned)(d_ & 511) << 17);
            bS = s_ >> 9; vS = (unsigned)(s_ & 511);
        }
        while (true) {
            if (t == 0) anyPend = 0;
            __syncthreads();
            if (pD) {
                int pos = atomicAdd(&lcntD[bD], 1);
                if (pos < 16) { stgD[bD][pos] = vD; pD = false; } else anyPend = 1;
            }
            if (pS) {
                int pos = atomicAdd(&lcntS[bS], 1);
                if (pos < 16) { stgS[bS][pos] = vS; pS = false; } else anyPend = 1;
            }
            __syncthreads();
            int ap = anyPend;
            if (lcntD[t] >= 16) {
                int gp = atomicAdd(&gcurD[t], 16);
                uint4* dp = (uint4*)&tmpD[gp];
                const uint4* sp = (const uint4*)stgD[t];
                dp[0] = sp[0]; dp[1] = sp[1]; dp[2] = sp[2]; dp[3] = sp[3];
                lcntD[t] = 0;
            }
            if (lcntS[t] >= 16) {
                int gp = atomicAdd(&gcurS[t], 16);
                uint4* dp = (uint4*)&tmpS[gp];
                const uint4* sp = (const uint4*)stgS[t];
                dp[0] = sp[0]; dp[1] = sp[1]; dp[2] = sp[2]; dp[3] = sp[3];
                lcntS[t] = 0;
            }
            if (!ap) break;
            __syncthreads();
        }
        __syncthreads();
    }
    int cD = lcntD[t];
    if (t < NB && cD > 0) {
        int gp = atomicAdd(&gcurD[t], 16);
        for (int i = 0; i < 16; i++) tmpD[gp + i] = (i < cD) ? stgD[t][i] : 0xFFFFFFFFu;
    }
    int cS = lcntS[t];
    if (t < NB && cS > 0) {
        int gp = atomicAdd(&gcurS[t], 16);
        for (int i = 0; i < 16; i++) tmpS[gp + i] = (i < cS) ? stgS[t][i] : 0xFFFFFFFFu;
    }
}

// ---------------- src-bucket count -> ns ----------------
__global__ __launch_bounds__(256) void k_cntS(const int* __restrict__ bbaseS,
    const int* __restrict__ gcurS, const unsigned* __restrict__ tmpS,
    float* __restrict__ ns, int N)
{
    __shared__ int cnt[512];
    int b = blockIdx.x, t = threadIdx.x;
    cnt[t] = 0; cnt[t + 256] = 0;
    __syncthreads();
    int beg = bbaseS[b], end = gcurS[b];
    for (int e = beg + t; e < end; e += 256) {
        unsigned v = tmpS[e];
        if (v != 0xFFFFFFFFu) atomicAdd(&cnt[v], 1);
    }
    __syncthreads();
    int nb = b << 9;
    for (int i = t; i < 512; i += 256) {
        int n = nb + i;
        if (n < N) ns[n] = rsqrtf(fmaxf((float)cnt[i], 1.0f));
    }
}

// ---------------- dst-bucket: degI + nd + rowptr (LDS scan) + CSR fill ----------------
__global__ __launch_bounds__(256) void k_csrD(const int* __restrict__ bbaseD,
    const int* __restrict__ gcurD, const int* __restrict__ ebase,
    const unsigned* __restrict__ tmpD, int* __restrict__ degI, float* __restrict__ nd,
    int* __restrict__ rowptr, int* __restrict__ srcIdx, int N)
{
    __shared__ int cnt[512];
    __shared__ int sblk[256];
    __shared__ int lcur[512];
    int b = blockIdx.x, t = threadIdx.x;
    cnt[t] = 0; cnt[t + 256] = 0;
    __syncthreads();
    int beg = bbaseD[b], end = gcurD[b];
    for (int e = beg + t; e < end; e += 256) {
        unsigned v = tmpD[e];
        if (v != 0xFFFFFFFFu) atomicAdd(&cnt[v >> 17], 1);
    }
    __syncthreads();
    int v0 = cnt[2 * t], v1 = cnt[2 * t + 1];
    sblk[t] = v0 + v1;
    __syncthreads();
#pragma unroll
    for (int off = 1; off < 256; off <<= 1) {
        int x = (t >= off) ? sblk[t - off] : 0;
        __syncthreads(); sblk[t] += x; __syncthreads();
    }
    int S = sblk[t];
    int eb = ebase[b];
    int e0 = eb + S - v0 - v1;
    int e1_ = e0 + v0;
    int nb = b << 9;
    int n0 = nb + 2 * t, n1 = n0 + 1;
    if (n0 < N) { rowptr[n0] = e0;  degI[n0] = v0; nd[n0] = rsqrtf(fmaxf((float)v0, 1.f)); }
    if (n1 < N) { rowptr[n1] = e1_; degI[n1] = v1; nd[n1] = rsqrtf(fmaxf((float)v1, 1.f)); }
    lcur[2 * t] = e0; lcur[2 * t + 1] = e1_;
    __syncthreads();
    for (int e = beg + t; e < end; e += 256) {
        unsigned v = tmpD[e];
        if (v == 0xFFFFFFFFu) continue;
        int pos = atomicAdd(&lcur[v >> 17], 1);
        srcIdx[pos] = (int)(v & 0x1FFFFu);
    }
}

// ---------------- W prep: transpose + bf16 split + XOR-swizzle ----------------
template<int DOUT>
__global__ __launch_bounds__(256) void k_prepW(const float* __restrict__ W,
    unsigned short* __restrict__ Wh, unsigned short* __restrict__ Wl)
{
    int idx = blockIdx.x * 256 + threadIdx.x;
    if (idx >= 128 * DOUT) return;
    int c = idx % DOUT;
    int k = idx / DOUT;
    float w = W[idx];
    unsigned short hi = f2bf(w);
    unsigned short lo = f2bf(w - bf2f(hi));
    int boff = c * 256 + ((2 * k) ^ ((c & 7) << 4));
    *(unsigned short*)((char*)Wh + boff) = hi;
    *(unsigned short*)((char*)Wl + boff) = lo;
}

// ---------------- MFMA GEMM: out[n][:] = f(in[n][:]) @ W  (DIN=128, bf16 out) ----------------
template<int DOUT, int MODE>
__global__ __launch_bounds__(256) void k_gemm_mfma(
    const float* __restrict__ in,
    const unsigned short* __restrict__ Wth, const unsigned short* __restrict__ Wtl,
    const float* __restrict__ bprev,
    const float* __restrict__ ns, const float* __restrict__ nd,
    unsigned short* __restrict__ out, int N)
{
    constexpr int NT = DOUT / 16;
    __shared__ __align__(16) unsigned short Wh[DOUT * 128];
    __shared__ __align__(16) unsigned short Wl[DOUT * 128];

    const int t = threadIdx.x;
    const int w = t >> 6, l = t & 63;

#pragma unroll
    for (int i = 0; i < DOUT * 256 / 4096; i++) {
        int off = i * 4096 + t * 16;
        *(float4*)((char*)Wh + off) = *(const float4*)((const char*)Wth + off);
        *(float4*)((char*)Wl + off) = *(const float4*)((const char*)Wtl + off);
    }

    const int rl   = l & 15;
    const int kgrp = l >> 4;
    const int row  = blockIdx.x * 64 + w * 16 + rl;
    const int rowc = row < N ? row : N - 1;
    const float* arow = in + (size_t)rowc * 128;

    float av[4][8];
#pragma unroll
    for (int ks = 0; ks < 4; ks++) {
        int kb = ks * 32 + kgrp * 8;
        float4 v0 = *(const float4*)(arow + kb);
        float4 v1 = *(const float4*)(arow + kb + 4);
        av[ks][0] = v0.x; av[ks][1] = v0.y; av[ks][2] = v0.z; av[ks][3] = v0.w;
        av[ks][4] = v1.x; av[ks][5] = v1.y; av[ks][6] = v1.z; av[ks][7] = v1.w;
    }
    if (MODE == 1) {
        float ndv = nd[rowc], nsv = ns[rowc];
#pragma unroll
        for (int ks = 0; ks < 4; ks++) {
            int kb = ks * 32 + kgrp * 8;
            float4 b0 = *(const float4*)(bprev + kb);
            float4 b1 = *(const float4*)(bprev + kb + 4);
            float bb[8] = {b0.x, b0.y, b0.z, b0.w, b1.x, b1.y, b1.z, b1.w};
#pragma unroll
            for (int j = 0; j < 8; j++)
                av[ks][j] = fmaxf(av[ks][j] * ndv + bb[j], 0.f) * nsv;
        }
    } else {
        float nsv = ns[rowc];
#pragma unroll
        for (int ks = 0; ks < 4; ks++)
#pragma unroll
            for (int j = 0; j < 8; j++)
                av[ks][j] *= nsv;
    }
    short8 Ah[4], Al[4];
#pragma unroll
    for (int ks = 0; ks < 4; ks++)
#pragma unroll
        for (int j = 0; j < 8; j++) {
            unsigned short hi = f2bf(av[ks][j]);
            Ah[ks][j] = (short)hi;
            Al[ks][j] = (short)f2bf(av[ks][j] - bf2f(hi));
        }

    __syncthreads();

    f32x4 acc[NT];
#pragma unroll
    for (int tt = 0; tt < NT; tt++) acc[tt] = (f32x4){0.f, 0.f, 0.f, 0.f};

#pragma unroll
    for (int ks = 0; ks < 4; ks++) {
        int kbyte = ks * 64 + kgrp * 16;
#pragma unroll
        for (int tt = 0; tt < NT; tt++) {
            int c = tt * 16 + rl;
            int boff = c * 256 + (kbyte ^ ((c & 7) << 4));
            short8 Bh = *(short8*)((char*)Wh + boff);
            short8 Bl = *(short8*)((char*)Wl + boff);
            acc[tt] = __builtin_amdgcn_mfma_f32_16x16x32_bf16(Ah[ks], Bh, acc[tt], 0, 0, 0);
            acc[tt] = __builtin_amdgcn_mfma_f32_16x16x32_bf16(Al[ks], Bh, acc[tt], 0, 0, 0);
            acc[tt] = __builtin_amdgcn_mfma_f32_16x16x32_bf16(Ah[ks], Bl, acc[tt], 0, 0, 0);
        }
    }

    const int orow = blockIdx.x * 64 + w * 16 + kgrp * 4;
#pragma unroll
    for (int r = 0; r < 4; r++) {
        if (orow + r < N) {
#pragma unroll
            for (int tt = 0; tt < NT; tt++)
                out[(size_t)(orow + r) * DOUT + tt * 16 + rl] = f2bf(acc[tt][r]);
        }
    }
}

// ---------------- pull-based aggregation (bf16 gather, f32 accumulate) ----------------
// D=128: 16 threads/node x 8 ch; D=64: 8 threads/node x 8 ch
template<int D, int FINAL>
__global__ __launch_bounds__(256) void k_agg(
    const int* __restrict__ rowptr, const int* __restrict__ cnt,
    const int* __restrict__ srcIdx, const unsigned short* __restrict__ h,
    const float* __restrict__ nd, const float* __restrict__ b3,
    float* __restrict__ m, int N)
{
    constexpr int TPN = D / 8;
    constexpr int NPB = 256 / TPN;
    int t = threadIdx.x;
    int node = blockIdx.x * NPB + t / TPN;
    if (node >= N) return;
    int c = (t % TPN) * 8;

    int beg = rowptr[node];
    int end = beg + cnt[node];
    float acc[8] = {0.f, 0.f, 0.f, 0.f, 0.f, 0.f, 0.f, 0.f};
    for (int e = beg; e < end; e++) {
        int s = srcIdx[e];
        u16x8 v = *(const u16x8*)&h[(size_t)s * D + c];
#pragma unroll
        for (int j = 0; j < 8; j++) acc[j] += bf2f(v[j]);
    }
    if (FINAL) {
        float ndv = nd[node];
#pragma unroll
        for (int j = 0; j < 8; j++) acc[j] = acc[j] * ndv + b3[c + j];
    }
    float4* mp = (float4*)&m[(size_t)node * D + c];
    mp[0] = make_float4(acc[0], acc[1], acc[2], acc[3]);
    mp[1] = make_float4(acc[4], acc[5], acc[6], acc[7]);
}

extern "C" void kernel_launch(void* const* d_in, const int* in_sizes, int n_in,
                              void* d_out, int out_size, void* d_ws, size_t ws_size,
                              hipStream_t stream) {
    const float* x  = (const float*)d_in[0];
    const int*   src = (const int*)d_in[1];
    const int*   dst = (const int*)d_in[2];
    const float* W1 = (const float*)d_in[3];
    const float* b1 = (const float*)d_in[4];
    const float* W2 = (const float*)d_in[5];
    const float* b2 = (const float*)d_in[6];
    const float* W3 = (const float*)d_in[7];
    const float* b3 = (const float*)d_in[8];
    float* out = (float*)d_out;

    const int N = NN;
    const int E = in_sizes[1];

    char* ws = (char*)d_ws;
    unsigned short* bufA = (unsigned short*)ws;                 // h: N*128 bf16 (aliases tmpD)
    float* bufB  = (float*)(ws + (size_t)N * 128 * 4);          // m: N*128 f32 (aliases tmpS)
    unsigned* tmpD = (unsigned*)bufA;                           // consumed before gemm1 writes bufA
    unsigned* tmpS = (unsigned*)bufB;                           // consumed before agg1 writes bufB
    char*  p     = ws + (size_t)N * 128 * 4 * 2;
    float* ns    = (float*)p;              p += (size_t)N * 4;
    float* nd    = (float*)p;              p += (size_t)N * 4;
    int*   degI  = (int*)p;                p += (size_t)N * 4;
    int*   rowp  = (int*)p;                p += (size_t)N * 4;
    int*   srcIdx= (int*)p;                p += (size_t)E * 4;
    unsigned short* W1h = (unsigned short*)p; p += 128 * 128 * 2;
    unsigned short* W1l = (unsigned short*)p; p += 128 * 128 * 2;
    unsigned short* W2h = (unsigned short*)p; p += 128 * 128 * 2;
    unsigned short* W2l = (unsigned short*)p; p += 128 * 128 * 2;
    unsigned short* W3h = (unsigned short*)p; p += 64 * 128 * 2;
    unsigned short* W3l = (unsigned short*)p; p += 64 * 128 * 2;
    int* bcntS = (int*)p;                  p += 256 * 4;
    int* bcntD = (int*)p;                  p += 256 * 4;
    int* bbaseS= (int*)p;                  p += 256 * 4;
    int* bbaseD= (int*)p;                  p += 256 * 4;
    int* gcurS = (int*)p;                  p += 256 * 4;
    int* gcurD = (int*)p;                  p += 256 * 4;
    int* ebase = (int*)p;                  p += 256 * 4;

    // W prep (independent)
    k_prepW<128><<<64, 256, 0, stream>>>(W1, W1h, W1l);
    k_prepW<128><<<64, 256, 0, stream>>>(W2, W2h, W2l);
    k_prepW<64><<<32, 256, 0, stream>>>(W3, W3h, W3l);

    // bucketed degree/CSR pipeline (no per-edge global atomics)
    hipMemsetAsync(bcntS, 0, 2 * 256 * 4, stream);
    k_bhist2<<<192, 256, 0, stream>>>(src, dst, bcntS, bcntD, E);
    k_bscan2<<<1, 256, 0, stream>>>(bcntS, bcntD, bbaseS, gcurS, bbaseD, gcurD, ebase);
    k_bscatter2<<<PB_BLOCKS, 256, 0, stream>>>(src, dst, gcurD, gcurS, tmpD, tmpS, E);
    k_cntS<<<NB, 256, 0, stream>>>(bbaseS, gcurS, tmpS, ns, N);
    k_csrD<<<NB, 256, 0, stream>>>(bbaseD, gcurD, ebase, tmpD, degI, nd, rowp, srcIdx, N);

    const int gemm_grid = (N + 63) / 64;
    const int agg128 = (N + 15) / 16;
    const int agg64  = (N + 31) / 32;

    // ---- layer 1 ----
    k_gemm_mfma<128, 0><<<gemm_grid, 256, 0, stream>>>(x, W1h, W1l, nullptr, ns, nd, bufA, N);
    k_agg<128, 0><<<agg128, 256, 0, stream>>>(rowp, degI, srcIdx, bufA, nd, b3, bufB, N);

    // ---- layer 2 ----
    k_gemm_mfma<128, 1><<<gemm_grid, 256, 0, stream>>>(bufB, W2h, W2l, b1, ns, nd, bufA, N);
    k_agg<128, 0><<<agg128, 256, 0, stream>>>(rowp, degI, srcIdx, bufA, nd, b3, bufB, N);

    // ---- layer 3 (final epilogue fused) ----
    k_gemm_mfma<64, 1><<<gemm_grid, 256, 0, stream>>>(bufB, W3h, W3l, b2, ns, nd, bufA, N);
    k_agg<64, 1><<<agg64, 256, 0, stream>>>(rowp, degI, srcIdx, bufA, nd, b3, out, N);
}

// Round 7
// 340.781 us; speedup vs baseline: 20.5447x; 1.2123x over previous
//
#include <hip/hip_runtime.h>

#define NN 100000
#define NB 196            // ceil(NN / 512) buckets of 512 nodes
#define CH 4096           // edges per block in k_bscatter3

typedef short short8 __attribute__((ext_vector_type(8)));
typedef unsigned short u16x8 __attribute__((ext_vector_type(8)));
typedef float f32x4 __attribute__((ext_vector_type(4)));

__device__ inline unsigned short f2bf(float x) {
    unsigned u = __float_as_uint(x);
    unsigned r = (u + 0x7FFF + ((u >> 16) & 1)) >> 16;
    return (unsigned short)r;
}
__device__ inline float bf2f(unsigned short h) {
    return __uint_as_float(((unsigned)h) << 16);
}

// ---------------- bucket histograms (src & dst) via LDS ----------------
__global__ __launch_bounds__(256) void k_bhist2(const int* __restrict__ src,
    const int* __restrict__ dst, int* __restrict__ bcntS, int* __restrict__ bcntD, int E)
{
    __shared__ int hs[NB], hd[NB];
    int t = threadIdx.x;
    if (t < NB) { hs[t] = 0; hd[t] = 0; }
    __syncthreads();
    int stride = gridDim.x * 256;
    for (int e = blockIdx.x * 256 + t; e < E; e += stride) {
        atomicAdd(&hs[src[e] >> 9], 1);
        atomicAdd(&hd[dst[e] >> 9], 1);
    }
    __syncthreads();
    if (t < NB) {
        if (hs[t]) atomicAdd(&bcntS[t], hs[t]);
        if (hd[t]) atomicAdd(&bcntD[t], hd[t]);
    }
}

// ---------------- exact bucket scans (dense tmp layout) ----------------
__global__ __launch_bounds__(256) void k_bscan2(const int* __restrict__ bcntS,
    const int* __restrict__ bcntD, int* __restrict__ bbaseS, int* __restrict__ gcurS,
    int* __restrict__ bbaseD, int* __restrict__ gcurD)
{
    __shared__ int s[256];
    int t = threadIdx.x;
    int cD = (t < NB) ? bcntD[t] : 0;
    int cS = (t < NB) ? bcntS[t] : 0;

    int v = cD;
    s[t] = v;
    __syncthreads();
#pragma unroll
    for (int off = 1; off < 256; off <<= 1) {
        int x = (t >= off) ? s[t - off] : 0;
        __syncthreads(); s[t] += x; __syncthreads();
    }
    if (t < NB) { int e = s[t] - v; bbaseD[t] = e; gcurD[t] = e; }
    __syncthreads();

    v = cS;
    s[t] = v;
    __syncthreads();
#pragma unroll
    for (int off = 1; off < 256; off <<= 1) {
        int x = (t >= off) ? s[t - off] : 0;
        __syncthreads(); s[t] += x; __syncthreads();
    }
    if (t < NB) { int e = s[t] - v; bbaseS[t] = e; gcurS[t] = e; }
}

// ---------------- one-shot counting-claim bucket scatter ----------------
__global__ __launch_bounds__(256) void k_bscatter3(const int* __restrict__ src,
    const int* __restrict__ dst, int* __restrict__ gcurD, int* __restrict__ gcurS,
    unsigned* __restrict__ tmpD, unsigned* __restrict__ tmpS, int E)
{
    __shared__ int cntD[NB], cntS[NB];
    __shared__ int runD[NB], runS[NB];
    int t = threadIdx.x;
    if (t < NB) { cntD[t] = 0; cntS[t] = 0; }
    __syncthreads();

    const int e0 = blockIdx.x * CH;
    int sv[16], dv[16];
    int offD[16], offS[16];
#pragma unroll
    for (int i = 0; i < 16; i++) {
        int e = e0 + i * 256 + t;
        if (e < E) { sv[i] = src[e]; dv[i] = dst[e]; }
    }
#pragma unroll
    for (int i = 0; i < 16; i++) {
        int e = e0 + i * 256 + t;
        if (e < E) {
            offD[i] = atomicAdd(&cntD[dv[i] >> 9], 1);
            offS[i] = atomicAdd(&cntS[sv[i] >> 9], 1);
        }
    }
    __syncthreads();
    if (t < NB) {
        int c = cntD[t];
        if (c) runD[t] = atomicAdd(&gcurD[t], c);
        c = cntS[t];
        if (c) runS[t] = atomicAdd(&gcurS[t], c);
    }
    __syncthreads();
#pragma unroll
    for (int i = 0; i < 16; i++) {
        int e = e0 + i * 256 + t;
        if (e < E) {
            int bD = dv[i] >> 9;
            tmpD[runD[bD] + offD[i]] = (unsigned)sv[i] | ((unsigned)(dv[i] & 511) << 17);
            int bS = sv[i] >> 9;
            tmpS[runS[bS] + offS[i]] = (unsigned)(sv[i] & 511);
        }
    }
}

// ---------------- src-bucket count -> ns ----------------
__global__ __launch_bounds__(256) void k_cntS(const int* __restrict__ bbaseS,
    const int* __restrict__ bcntS, const unsigned* __restrict__ tmpS,
    float* __restrict__ ns, int N)
{
    __shared__ int cnt[512];
    int b = blockIdx.x, t = threadIdx.x;
    cnt[t] = 0; cnt[t + 256] = 0;
    __syncthreads();
    int beg = bbaseS[b], end = beg + bcntS[b];
    for (int e = beg + t; e < end; e += 256)
        atomicAdd(&cnt[tmpS[e]], 1);
    __syncthreads();
    int nb = b << 9;
    for (int i = t; i < 512; i += 256) {
        int n = nb + i;
        if (n < N) ns[n] = rsqrtf(fmaxf((float)cnt[i], 1.0f));
    }
}

// ---------------- dst-bucket: degI + nd + rowptr (LDS scan) + CSR fill ----------------
__global__ __launch_bounds__(256) void k_csrD(const int* __restrict__ bbaseD,
    const int* __restrict__ bcntD, const unsigned* __restrict__ tmpD,
    int* __restrict__ degI, float* __restrict__ nd,
    int* __restrict__ rowptr, int* __restrict__ srcIdx, int N)
{
    __shared__ int cnt[512];
    __shared__ int sblk[256];
    __shared__ int lcur[512];
    int b = blockIdx.x, t = threadIdx.x;
    cnt[t] = 0; cnt[t + 256] = 0;
    __syncthreads();
    int beg = bbaseD[b], end = beg + bcntD[b];
    for (int e = beg + t; e < end; e += 256)
        atomicAdd(&cnt[tmpD[e] >> 17], 1);
    __syncthreads();
    int v0 = cnt[2 * t], v1 = cnt[2 * t + 1];
    sblk[t] = v0 + v1;
    __syncthreads();
#pragma unroll
    for (int off = 1; off < 256; off <<= 1) {
        int x = (t >= off) ? sblk[t - off] : 0;
        __syncthreads(); sblk[t] += x; __syncthreads();
    }
    int S = sblk[t];
    int e0 = beg + S - v0 - v1;   // ebase == bbaseD (dense layout)
    int e1_ = e0 + v0;
    int nb = b << 9;
    int n0 = nb + 2 * t, n1 = n0 + 1;
    if (n0 < N) { rowptr[n0] = e0;  degI[n0] = v0; nd[n0] = rsqrtf(fmaxf((float)v0, 1.f)); }
    if (n1 < N) { rowptr[n1] = e1_; degI[n1] = v1; nd[n1] = rsqrtf(fmaxf((float)v1, 1.f)); }
    lcur[2 * t] = e0; lcur[2 * t + 1] = e1_;
    __syncthreads();
    for (int e = beg + t; e < end; e += 256) {
        unsigned v = tmpD[e];
        int pos = atomicAdd(&lcur[v >> 17], 1);
        srcIdx[pos] = (int)(v & 0x1FFFFu);
    }
}

// ---------------- W prep: transpose + bf16 split + XOR-swizzle ----------------
template<int DOUT>
__global__ __launch_bounds__(256) void k_prepW(const float* __restrict__ W,
    unsigned short* __restrict__ Wh, unsigned short* __restrict__ Wl)
{
    int idx = blockIdx.x * 256 + threadIdx.x;
    if (idx >= 128 * DOUT) return;
    int c = idx % DOUT;
    int k = idx / DOUT;
    float w = W[idx];
    unsigned short hi = f2bf(w);
    unsigned short lo = f2bf(w - bf2f(hi));
    int boff = c * 256 + ((2 * k) ^ ((c & 7) << 4));
    *(unsigned short*)((char*)Wh + boff) = hi;
    *(unsigned short*)((char*)Wl + boff) = lo;
}

// ---------------- MFMA GEMM: out[n][:] = f(in[n][:]) @ W  (DIN=128, bf16 out) ----------------
template<int DOUT, int MODE>
__global__ __launch_bounds__(256) void k_gemm_mfma(
    const float* __restrict__ in,
    const unsigned short* __restrict__ Wth, const unsigned short* __restrict__ Wtl,
    const float* __restrict__ bprev,
    const float* __restrict__ ns, const float* __restrict__ nd,
    unsigned short* __restrict__ out, int N)
{
    constexpr int NT = DOUT / 16;
    __shared__ __align__(16) unsigned short Wh[DOUT * 128];
    __shared__ __align__(16) unsigned short Wl[DOUT * 128];

    const int t = threadIdx.x;
    const int w = t >> 6, l = t & 63;

#pragma unroll
    for (int i = 0; i < DOUT * 256 / 4096; i++) {
        int off = i * 4096 + t * 16;
        *(float4*)((char*)Wh + off) = *(const float4*)((const char*)Wth + off);
        *(float4*)((char*)Wl + off) = *(const float4*)((const char*)Wtl + off);
    }

    const int rl   = l & 15;
    const int kgrp = l >> 4;
    const int row  = blockIdx.x * 64 + w * 16 + rl;
    const int rowc = row < N ? row : N - 1;
    const float* arow = in + (size_t)rowc * 128;

    float av[4][8];
#pragma unroll
    for (int ks = 0; ks < 4; ks++) {
        int kb = ks * 32 + kgrp * 8;
        float4 v0 = *(const float4*)(arow + kb);
        float4 v1 = *(const float4*)(arow + kb + 4);
        av[ks][0] = v0.x; av[ks][1] = v0.y; av[ks][2] = v0.z; av[ks][3] = v0.w;
        av[ks][4] = v1.x; av[ks][5] = v1.y; av[ks][6] = v1.z; av[ks][7] = v1.w;
    }
    if (MODE == 1) {
        float ndv = nd[rowc], nsv = ns[rowc];
#pragma unroll
        for (int ks = 0; ks < 4; ks++) {
            int kb = ks * 32 + kgrp * 8;
            float4 b0 = *(const float4*)(bprev + kb);
            float4 b1 = *(const float4*)(bprev + kb + 4);
            float bb[8] = {b0.x, b0.y, b0.z, b0.w, b1.x, b1.y, b1.z, b1.w};
#pragma unroll
            for (int j = 0; j < 8; j++)
                av[ks][j] = fmaxf(av[ks][j] * ndv + bb[j], 0.f) * nsv;
        }
    } else {
        float nsv = ns[rowc];
#pragma unroll
        for (int ks = 0; ks < 4; ks++)
#pragma unroll
            for (int j = 0; j < 8; j++)
                av[ks][j] *= nsv;
    }
    short8 Ah[4], Al[4];
#pragma unroll
    for (int ks = 0; ks < 4; ks++)
#pragma unroll
        for (int j = 0; j < 8; j++) {
            unsigned short hi = f2bf(av[ks][j]);
            Ah[ks][j] = (short)hi;
            Al[ks][j] = (short)f2bf(av[ks][j] - bf2f(hi));
        }

    __syncthreads();

    f32x4 acc[NT];
#pragma unroll
    for (int tt = 0; tt < NT; tt++) acc[tt] = (f32x4){0.f, 0.f, 0.f, 0.f};

#pragma unroll
    for (int ks = 0; ks < 4; ks++) {
        int kbyte = ks * 64 + kgrp * 16;
#pragma unroll
        for (int tt = 0; tt < NT; tt++) {
            int c = tt * 16 + rl;
            int boff = c * 256 + (kbyte ^ ((c & 7) << 4));
            short8 Bh = *(short8*)((char*)Wh + boff);
            short8 Bl = *(short8*)((char*)Wl + boff);
            acc[tt] = __builtin_amdgcn_mfma_f32_16x16x32_bf16(Ah[ks], Bh, acc[tt], 0, 0, 0);
            acc[tt] = __builtin_amdgcn_mfma_f32_16x16x32_bf16(Al[ks], Bh, acc[tt], 0, 0, 0);
            acc[tt] = __builtin_amdgcn_mfma_f32_16x16x32_bf16(Ah[ks], Bl, acc[tt], 0, 0, 0);
        }
    }

    const int orow = blockIdx.x * 64 + w * 16 + kgrp * 4;
#pragma unroll
    for (int r = 0; r < 4; r++) {
        if (orow + r < N) {
#pragma unroll
            for (int tt = 0; tt < NT; tt++)
                out[(size_t)(orow + r) * DOUT + tt * 16 + rl] = f2bf(acc[tt][r]);
        }
    }
}

// ---------------- pull-based aggregation (bf16 gather, f32 accumulate) ----------------
template<int D, int FINAL>
__global__ __launch_bounds__(256) void k_agg(
    const int* __restrict__ rowptr, const int* __restrict__ cnt,
    const int* __restrict__ srcIdx, const unsigned short* __restrict__ h,
    const float* __restrict__ nd, const float* __restrict__ b3,
    float* __restrict__ m, int N)
{
    constexpr int TPN = D / 8;
    constexpr int NPB = 256 / TPN;
    int t = threadIdx.x;
    int node = blockIdx.x * NPB + t / TPN;
    if (node >= N) return;
    int c = (t % TPN) * 8;

    int beg = rowptr[node];
    int end = beg + cnt[node];
    float acc[8] = {0.f, 0.f, 0.f, 0.f, 0.f, 0.f, 0.f, 0.f};
    for (int e = beg; e < end; e++) {
        int s = srcIdx[e];
        u16x8 v = *(const u16x8*)&h[(size_t)s * D + c];
#pragma unroll
        for (int j = 0; j < 8; j++) acc[j] += bf2f(v[j]);
    }
    if (FINAL) {
        float ndv = nd[node];
#pragma unroll
        for (int j = 0; j < 8; j++) acc[j] = acc[j] * ndv + b3[c + j];
    }
    float4* mp = (float4*)&m[(size_t)node * D + c];
    mp[0] = make_float4(acc[0], acc[1], acc[2], acc[3]);
    mp[1] = make_float4(acc[4], acc[5], acc[6], acc[7]);
}

extern "C" void kernel_launch(void* const* d_in, const int* in_sizes, int n_in,
                              void* d_out, int out_size, void* d_ws, size_t ws_size,
                              hipStream_t stream) {
    const float* x  = (const float*)d_in[0];
    const int*   src = (const int*)d_in[1];
    const int*   dst = (const int*)d_in[2];
    const float* W1 = (const float*)d_in[3];
    const float* b1 = (const float*)d_in[4];
    const float* W2 = (const float*)d_in[5];
    const float* b2 = (const float*)d_in[6];
    const float* W3 = (const float*)d_in[7];
    const float* b3 = (const float*)d_in[8];
    float* out = (float*)d_out;

    const int N = NN;
    const int E = in_sizes[1];

    char* ws = (char*)d_ws;
    unsigned short* bufA = (unsigned short*)ws;                 // h: N*128 bf16 (aliases tmpD)
    float* bufB  = (float*)(ws + (size_t)N * 128 * 4);          // m: N*128 f32 (aliases tmpS)
    unsigned* tmpD = (unsigned*)bufA;                           // consumed before gemm1 writes bufA
    unsigned* tmpS = (unsigned*)bufB;                           // consumed before agg1 writes bufB
    char*  p     = ws + (size_t)N * 128 * 4 * 2;
    float* ns    = (float*)p;              p += (size_t)N * 4;
    float* nd    = (float*)p;              p += (size_t)N * 4;
    int*   degI  = (int*)p;                p += (size_t)N * 4;
    int*   rowp  = (int*)p;                p += (size_t)N * 4;
    int*   srcIdx= (int*)p;                p += (size_t)E * 4;
    unsigned short* W1h = (unsigned short*)p; p += 128 * 128 * 2;
    unsigned short* W1l = (unsigned short*)p; p += 128 * 128 * 2;
    unsigned short* W2h = (unsigned short*)p; p += 128 * 128 * 2;
    unsigned short* W2l = (unsigned short*)p; p += 128 * 128 * 2;
    unsigned short* W3h = (unsigned short*)p; p += 64 * 128 * 2;
    unsigned short* W3l = (unsigned short*)p; p += 64 * 128 * 2;
    int* bcntS = (int*)p;                  p += 256 * 4;
    int* bcntD = (int*)p;                  p += 256 * 4;
    int* bbaseS= (int*)p;                  p += 256 * 4;
    int* bbaseD= (int*)p;                  p += 256 * 4;
    int* gcurS = (int*)p;                  p += 256 * 4;
    int* gcurD = (int*)p;                  p += 256 * 4;

    // W prep (independent)
    k_prepW<128><<<64, 256, 0, stream>>>(W1, W1h, W1l);
    k_prepW<128><<<64, 256, 0, stream>>>(W2, W2h, W2l);
    k_prepW<64><<<32, 256, 0, stream>>>(W3, W3h, W3l);

    // bucketed degree/CSR pipeline (no per-edge global atomics)
    hipMemsetAsync(bcntS, 0, 2 * 256 * 4, stream);
    k_bhist2<<<192, 256, 0, stream>>>(src, dst, bcntS, bcntD, E);
    k_bscan2<<<1, 256, 0, stream>>>(bcntS, bcntD, bbaseS, gcurS, bbaseD, gcurD);
    k_bscatter3<<<(E + CH - 1) / CH, 256, 0, stream>>>(src, dst, gcurD, gcurS, tmpD, tmpS, E);
    k_cntS<<<NB, 256, 0, stream>>>(bbaseS, bcntS, tmpS, ns, N);
    k_csrD<<<NB, 256, 0, stream>>>(bbaseD, bcntD, tmpD, degI, nd, rowp, srcIdx, N);

    const int gemm_grid = (N + 63) / 64;
    const int agg128 = (N + 15) / 16;
    const int agg64  = (N + 31) / 32;

    // ---- layer 1 ----
    k_gemm_mfma<128, 0><<<gemm_grid, 256, 0, stream>>>(x, W1h, W1l, nullptr, ns, nd, bufA, N);
    k_agg<128, 0><<<agg128, 256, 0, stream>>>(rowp, degI, srcIdx, bufA, nd, b3, bufB, N);

    // ---- layer 2 ----
    k_gemm_mfma<128, 1><<<gemm_grid, 256, 0, stream>>>(bufB, W2h, W2l, b1, ns, nd, bufA, N);
    k_agg<128, 0><<<agg128, 256, 0, stream>>>(rowp, degI, srcIdx, bufA, nd, b3, bufB, N);

    // ---- layer 3 (final epilogue fused) ----
    k_gemm_mfma<64, 1><<<gemm_grid, 256, 0, stream>>>(bufB, W3h, W3l, b2, ns, nd, bufA, N);
    k_agg<64, 1><<<agg64, 256, 0, stream>>>(rowp, degI, srcIdx, bufA, nd, b3, out, N);
}

// Round 8
// 338.531 us; speedup vs baseline: 20.6812x; 1.0066x over previous
//
#include <hip/hip_runtime.h>

#define NN 100000
#define NB 196            // ceil(NN / 512) buckets of 512 nodes
#define CH 4096           // edges per block in k_bscatter3

typedef short short8 __attribute__((ext_vector_type(8)));
typedef unsigned short u16x8 __attribute__((ext_vector_type(8)));
typedef float f32x4 __attribute__((ext_vector_type(4)));

__device__ inline unsigned short f2bf(float x) {
    unsigned u = __float_as_uint(x);
    unsigned r = (u + 0x7FFF + ((u >> 16) & 1)) >> 16;
    return (unsigned short)r;
}
__device__ inline float bf2f(unsigned short h) {
    return __uint_as_float(((unsigned)h) << 16);
}

// ---------------- bucket histograms (src & dst) via LDS ----------------
__global__ __launch_bounds__(256) void k_bhist2(const int* __restrict__ src,
    const int* __restrict__ dst, int* __restrict__ bcntS, int* __restrict__ bcntD, int E)
{
    __shared__ int hs[NB], hd[NB];
    int t = threadIdx.x;
    if (t < NB) { hs[t] = 0; hd[t] = 0; }
    __syncthreads();
    int stride = gridDim.x * 256;
    for (int e = blockIdx.x * 256 + t; e < E; e += stride) {
        atomicAdd(&hs[src[e] >> 9], 1);
        atomicAdd(&hd[dst[e] >> 9], 1);
    }
    __syncthreads();
    if (t < NB) {
        if (hs[t]) atomicAdd(&bcntS[t], hs[t]);
        if (hd[t]) atomicAdd(&bcntD[t], hd[t]);
    }
}

// ---------------- exact bucket scans (dense tmp layout) ----------------
__global__ __launch_bounds__(256) void k_bscan2(const int* __restrict__ bcntS,
    const int* __restrict__ bcntD, int* __restrict__ bbaseS, int* __restrict__ gcurS,
    int* __restrict__ bbaseD, int* __restrict__ gcurD)
{
    __shared__ int s[256];
    int t = threadIdx.x;
    int cD = (t < NB) ? bcntD[t] : 0;
    int cS = (t < NB) ? bcntS[t] : 0;

    int v = cD;
    s[t] = v;
    __syncthreads();
#pragma unroll
    for (int off = 1; off < 256; off <<= 1) {
        int x = (t >= off) ? s[t - off] : 0;
        __syncthreads(); s[t] += x; __syncthreads();
    }
    if (t < NB) { int e = s[t] - v; bbaseD[t] = e; gcurD[t] = e; }
    __syncthreads();

    v = cS;
    s[t] = v;
    __syncthreads();
#pragma unroll
    for (int off = 1; off < 256; off <<= 1) {
        int x = (t >= off) ? s[t - off] : 0;
        __syncthreads(); s[t] += x; __syncthreads();
    }
    if (t < NB) { int e = s[t] - v; bbaseS[t] = e; gcurS[t] = e; }
}

// ---------------- one-shot counting-claim bucket scatter ----------------
__global__ __launch_bounds__(256) void k_bscatter3(const int* __restrict__ src,
    const int* __restrict__ dst, int* __restrict__ gcurD, int* __restrict__ gcurS,
    unsigned* __restrict__ tmpD, unsigned* __restrict__ tmpS, int E)
{
    __shared__ int cntD[NB], cntS[NB];
    __shared__ int runD[NB], runS[NB];
    int t = threadIdx.x;
    if (t < NB) { cntD[t] = 0; cntS[t] = 0; }
    __syncthreads();

    const int e0 = blockIdx.x * CH;
    int sv[16], dv[16];
    int offD[16], offS[16];
#pragma unroll
    for (int i = 0; i < 16; i++) {
        int e = e0 + i * 256 + t;
        if (e < E) { sv[i] = src[e]; dv[i] = dst[e]; }
    }
#pragma unroll
    for (int i = 0; i < 16; i++) {
        int e = e0 + i * 256 + t;
        if (e < E) {
            offD[i] = atomicAdd(&cntD[dv[i] >> 9], 1);
            offS[i] = atomicAdd(&cntS[sv[i] >> 9], 1);
        }
    }
    __syncthreads();
    if (t < NB) {
        int c = cntD[t];
        if (c) runD[t] = atomicAdd(&gcurD[t], c);
        c = cntS[t];
        if (c) runS[t] = atomicAdd(&gcurS[t], c);
    }
    __syncthreads();
#pragma unroll
    for (int i = 0; i < 16; i++) {
        int e = e0 + i * 256 + t;
        if (e < E) {
            int bD = dv[i] >> 9;
            tmpD[runD[bD] + offD[i]] = (unsigned)sv[i] | ((unsigned)(dv[i] & 511) << 17);
            int bS = sv[i] >> 9;
            tmpS[runS[bS] + offS[i]] = (unsigned)(sv[i] & 511);
        }
    }
}

// ---------------- src-bucket count -> ns ----------------
__global__ __launch_bounds__(256) void k_cntS(const int* __restrict__ bbaseS,
    const int* __restrict__ bcntS, const unsigned* __restrict__ tmpS,
    float* __restrict__ ns, int N)
{
    __shared__ int cnt[512];
    int b = blockIdx.x, t = threadIdx.x;
    cnt[t] = 0; cnt[t + 256] = 0;
    __syncthreads();
    int beg = bbaseS[b], end = beg + bcntS[b];
    for (int e = beg + t; e < end; e += 256)
        atomicAdd(&cnt[tmpS[e]], 1);
    __syncthreads();
    int nb = b << 9;
    for (int i = t; i < 512; i += 256) {
        int n = nb + i;
        if (n < N) ns[n] = rsqrtf(fmaxf((float)cnt[i], 1.0f));
    }
}

// ---------------- dst-bucket: degI + nd + rowptr + src-ordered CSR fill ----------------
// two-level counting sort: key = (dlocal<<4) | (src>>13)  -> per-node lists
// grouped into 16 ascending src-ranges (8192 nodes = 2 MB of h each)
__global__ __launch_bounds__(256) void k_csrD(const int* __restrict__ bbaseD,
    const int* __restrict__ bcntD, const unsigned* __restrict__ tmpD,
    int* __restrict__ degI, float* __restrict__ nd,
    int* __restrict__ rowptr, int* __restrict__ srcIdx, int N)
{
    __shared__ int cnt[8192];      // [dlocal][16 src-parts], 32 KB
    __shared__ int sblk[256];
    int b = blockIdx.x, t = threadIdx.x;
    for (int i = t; i < 8192; i += 256) cnt[i] = 0;
    __syncthreads();
    int beg = bbaseD[b], end = beg + bcntD[b];
    for (int e = beg + t; e < end; e += 256) {
        unsigned v = tmpD[e];
        int dl = v >> 17;
        int s  = (int)(v & 0x1FFFFu);
        atomicAdd(&cnt[(dl << 4) | (s >> 13)], 1);
    }
    __syncthreads();
    // thread t owns keys [t*32, t*32+32) == nodes 2t, 2t+1
    int loc[32];
    int sum = 0;
#pragma unroll
    for (int i = 0; i < 32; i++) { loc[i] = sum; sum += cnt[t * 32 + i]; }
    sblk[t] = sum;
    __syncthreads();
#pragma unroll
    for (int off = 1; off < 256; off <<= 1) {
        int x = (t >= off) ? sblk[t - off] : 0;
        __syncthreads(); sblk[t] += x; __syncthreads();
    }
    int base = beg + sblk[t] - sum;     // exclusive scan + bucket base (dense layout)
    int v0 = loc[16];                   // deg of node 2t
    int v1 = sum - loc[16];             // deg of node 2t+1
    int nb = b << 9;
    int n0 = nb + 2 * t, n1 = n0 + 1;
    if (n0 < N) { rowptr[n0] = base;           degI[n0] = v0; nd[n0] = rsqrtf(fmaxf((float)v0, 1.f)); }
    if (n1 < N) { rowptr[n1] = base + loc[16]; degI[n1] = v1; nd[n1] = rsqrtf(fmaxf((float)v1, 1.f)); }
#pragma unroll
    for (int i = 0; i < 32; i++) cnt[t * 32 + i] = base + loc[i];   // turn into cursors
    __syncthreads();
    for (int e = beg + t; e < end; e += 256) {
        unsigned v = tmpD[e];
        int dl = v >> 17;
        int s  = (int)(v & 0x1FFFFu);
        int pos = atomicAdd(&cnt[(dl << 4) | (s >> 13)], 1);
        srcIdx[pos] = s;
    }
}

// ---------------- W prep: transpose + bf16 split + XOR-swizzle ----------------
template<int DOUT>
__global__ __launch_bounds__(256) void k_prepW(const float* __restrict__ W,
    unsigned short* __restrict__ Wh, unsigned short* __restrict__ Wl)
{
    int idx = blockIdx.x * 256 + threadIdx.x;
    if (idx >= 128 * DOUT) return;
    int c = idx % DOUT;
    int k = idx / DOUT;
    float w = W[idx];
    unsigned short hi = f2bf(w);
    unsigned short lo = f2bf(w - bf2f(hi));
    int boff = c * 256 + ((2 * k) ^ ((c & 7) << 4));
    *(unsigned short*)((char*)Wh + boff) = hi;
    *(unsigned short*)((char*)Wl + boff) = lo;
}

// ---------------- MFMA GEMM: out[n][:] = f(in[n][:]) @ W  (DIN=128, bf16 out) ----------------
template<int DOUT, int MODE>
__global__ __launch_bounds__(256) void k_gemm_mfma(
    const float* __restrict__ in,
    const unsigned short* __restrict__ Wth, const unsigned short* __restrict__ Wtl,
    const float* __restrict__ bprev,
    const float* __restrict__ ns, const float* __restrict__ nd,
    unsigned short* __restrict__ out, int N)
{
    constexpr int NT = DOUT / 16;
    __shared__ __align__(16) unsigned short Wh[DOUT * 128];
    __shared__ __align__(16) unsigned short Wl[DOUT * 128];

    const int t = threadIdx.x;
    const int w = t >> 6, l = t & 63;

#pragma unroll
    for (int i = 0; i < DOUT * 256 / 4096; i++) {
        int off = i * 4096 + t * 16;
        *(float4*)((char*)Wh + off) = *(const float4*)((const char*)Wth + off);
        *(float4*)((char*)Wl + off) = *(const float4*)((const char*)Wtl + off);
    }

    const int rl   = l & 15;
    const int kgrp = l >> 4;
    const int row  = blockIdx.x * 64 + w * 16 + rl;
    const int rowc = row < N ? row : N - 1;
    const float* arow = in + (size_t)rowc * 128;

    float av[4][8];
#pragma unroll
    for (int ks = 0; ks < 4; ks++) {
        int kb = ks * 32 + kgrp * 8;
        float4 v0 = *(const float4*)(arow + kb);
        float4 v1 = *(const float4*)(arow + kb + 4);
        av[ks][0] = v0.x; av[ks][1] = v0.y; av[ks][2] = v0.z; av[ks][3] = v0.w;
        av[ks][4] = v1.x; av[ks][5] = v1.y; av[ks][6] = v1.z; av[ks][7] = v1.w;
    }
    if (MODE == 1) {
        float ndv = nd[rowc], nsv = ns[rowc];
#pragma unroll
        for (int ks = 0; ks < 4; ks++) {
            int kb = ks * 32 + kgrp * 8;
            float4 b0 = *(const float4*)(bprev + kb);
            float4 b1 = *(const float4*)(bprev + kb + 4);
            float bb[8] = {b0.x, b0.y, b0.z, b0.w, b1.x, b1.y, b1.z, b1.w};
#pragma unroll
            for (int j = 0; j < 8; j++)
                av[ks][j] = fmaxf(av[ks][j] * ndv + bb[j], 0.f) * nsv;
        }
    } else {
        float nsv = ns[rowc];
#pragma unroll
        for (int ks = 0; ks < 4; ks++)
#pragma unroll
            for (int j = 0; j < 8; j++)
                av[ks][j] *= nsv;
    }
    short8 Ah[4], Al[4];
#pragma unroll
    for (int ks = 0; ks < 4; ks++)
#pragma unroll
        for (int j = 0; j < 8; j++) {
            unsigned short hi = f2bf(av[ks][j]);
            Ah[ks][j] = (short)hi;
            Al[ks][j] = (short)f2bf(av[ks][j] - bf2f(hi));
        }

    __syncthreads();

    f32x4 acc[NT];
#pragma unroll
    for (int tt = 0; tt < NT; tt++) acc[tt] = (f32x4){0.f, 0.f, 0.f, 0.f};

#pragma unroll
    for (int ks = 0; ks < 4; ks++) {
        int kbyte = ks * 64 + kgrp * 16;
#pragma unroll
        for (int tt = 0; tt < NT; tt++) {
            int c = tt * 16 + rl;
            int boff = c * 256 + (kbyte ^ ((c & 7) << 4));
            short8 Bh = *(short8*)((char*)Wh + boff);
            short8 Bl = *(short8*)((char*)Wl + boff);
            acc[tt] = __builtin_amdgcn_mfma_f32_16x16x32_bf16(Ah[ks], Bh, acc[tt], 0, 0, 0);
            acc[tt] = __builtin_amdgcn_mfma_f32_16x16x32_bf16(Al[ks], Bh, acc[tt], 0, 0, 0);
            acc[tt] = __builtin_amdgcn_mfma_f32_16x16x32_bf16(Ah[ks], Bl, acc[tt], 0, 0, 0);
        }
    }

    const int orow = blockIdx.x * 64 + w * 16 + kgrp * 4;
#pragma unroll
    for (int r = 0; r < 4; r++) {
        if (orow + r < N) {
#pragma unroll
            for (int tt = 0; tt < NT; tt++)
                out[(size_t)(orow + r) * DOUT + tt * 16 + rl] = f2bf(acc[tt][r]);
        }
    }
}

// ---------------- pull-based aggregation (bf16 gather, f32 accumulate) ----------------
template<int D, int FINAL>
__global__ __launch_bounds__(256) void k_agg(
    const int* __restrict__ rowptr, const int* __restrict__ cnt,
    const int* __restrict__ srcIdx, const unsigned short* __restrict__ h,
    const float* __restrict__ nd, const float* __restrict__ b3,
    float* __restrict__ m, int N)
{
    constexpr int TPN = D / 8;
    constexpr int NPB = 256 / TPN;
    int t = threadIdx.x;
    int node = blockIdx.x * NPB + t / TPN;
    if (node >= N) return;
    int c = (t % TPN) * 8;

    int beg = rowptr[node];
    int end = beg + cnt[node];
    float acc[8] = {0.f, 0.f, 0.f, 0.f, 0.f, 0.f, 0.f, 0.f};
    for (int e = beg; e < end; e++) {
        int s = srcIdx[e];
        u16x8 v = *(const u16x8*)&h[(size_t)s * D + c];
#pragma unroll
        for (int j = 0; j < 8; j++) acc[j] += bf2f(v[j]);
    }
    if (FINAL) {
        float ndv = nd[node];
#pragma unroll
        for (int j = 0; j < 8; j++) acc[j] = acc[j] * ndv + b3[c + j];
    }
    float4* mp = (float4*)&m[(size_t)node * D + c];
    mp[0] = make_float4(acc[0], acc[1], acc[2], acc[3]);
    mp[1] = make_float4(acc[4], acc[5], acc[6], acc[7]);
}

extern "C" void kernel_launch(void* const* d_in, const int* in_sizes, int n_in,
                              void* d_out, int out_size, void* d_ws, size_t ws_size,
                              hipStream_t stream) {
    const float* x  = (const float*)d_in[0];
    const int*   src = (const int*)d_in[1];
    const int*   dst = (const int*)d_in[2];
    const float* W1 = (const float*)d_in[3];
    const float* b1 = (const float*)d_in[4];
    const float* W2 = (const float*)d_in[5];
    const float* b2 = (const float*)d_in[6];
    const float* W3 = (const float*)d_in[7];
    const float* b3 = (const float*)d_in[8];
    float* out = (float*)d_out;

    const int N = NN;
    const int E = in_sizes[1];

    char* ws = (char*)d_ws;
    unsigned short* bufA = (unsigned short*)ws;                 // h: N*128 bf16 (aliases tmpD)
    float* bufB  = (float*)(ws + (size_t)N * 128 * 4);          // m: N*128 f32 (aliases tmpS)
    unsigned* tmpD = (unsigned*)bufA;                           // consumed before gemm1 writes bufA
    unsigned* tmpS = (unsigned*)bufB;                           // consumed before agg1 writes bufB
    char*  p     = ws + (size_t)N * 128 * 4 * 2;
    float* ns    = (float*)p;              p += (size_t)N * 4;
    float* nd    = (float*)p;              p += (size_t)N * 4;
    int*   degI  = (int*)p;                p += (size_t)N * 4;
    int*   rowp  = (int*)p;                p += (size_t)N * 4;
    int*   srcIdx= (int*)p;                p += (size_t)E * 4;
    unsigned short* W1h = (unsigned short*)p; p += 128 * 128 * 2;
    unsigned short* W1l = (unsigned short*)p; p += 128 * 128 * 2;
    unsigned short* W2h = (unsigned short*)p; p += 128 * 128 * 2;
    unsigned short* W2l = (unsigned short*)p; p += 128 * 128 * 2;
    unsigned short* W3h = (unsigned short*)p; p += 64 * 128 * 2;
    unsigned short* W3l = (unsigned short*)p; p += 64 * 128 * 2;
    int* bcntS = (int*)p;                  p += 256 * 4;
    int* bcntD = (int*)p;                  p += 256 * 4;
    int* bbaseS= (int*)p;                  p += 256 * 4;
    int* bbaseD= (int*)p;                  p += 256 * 4;
    int* gcurS = (int*)p;                  p += 256 * 4;
    int* gcurD = (int*)p;                  p += 256 * 4;

    // W prep (independent)
    k_prepW<128><<<64, 256, 0, stream>>>(W1, W1h, W1l);
    k_prepW<128><<<64, 256, 0, stream>>>(W2, W2h, W2l);
    k_prepW<64><<<32, 256, 0, stream>>>(W3, W3h, W3l);

    // bucketed degree/CSR pipeline (no per-edge global atomics)
    hipMemsetAsync(bcntS, 0, 2 * 256 * 4, stream);
    k_bhist2<<<192, 256, 0, stream>>>(src, dst, bcntS, bcntD, E);
    k_bscan2<<<1, 256, 0, stream>>>(bcntS, bcntD, bbaseS, gcurS, bbaseD, gcurD);
    k_bscatter3<<<(E + CH - 1) / CH, 256, 0, stream>>>(src, dst, gcurD, gcurS, tmpD, tmpS, E);
    k_cntS<<<NB, 256, 0, stream>>>(bbaseS, bcntS, tmpS, ns, N);
    k_csrD<<<NB, 256, 0, stream>>>(bbaseD, bcntD, tmpD, degI, nd, rowp, srcIdx, N);

    const int gemm_grid = (N + 63) / 64;
    const int agg128 = (N + 15) / 16;
    const int agg64  = (N + 31) / 32;

    // ---- layer 1 ----
    k_gemm_mfma<128, 0><<<gemm_grid, 256, 0, stream>>>(x, W1h, W1l, nullptr, ns, nd, bufA, N);
    k_agg<128, 0><<<agg128, 256, 0, stream>>>(rowp, degI, srcIdx, bufA, nd, b3, bufB, N);

    // ---- layer 2 ----
    k_gemm_mfma<128, 1><<<gemm_grid, 256, 0, stream>>>(bufB, W2h, W2l, b1, ns, nd, bufA, N);
    k_agg<128, 0><<<agg128, 256, 0, stream>>>(rowp, degI, srcIdx, bufA, nd, b3, bufB, N);

    // ---- layer 3 (final epilogue fused) ----
    k_gemm_mfma<64, 1><<<gemm_grid, 256, 0, stream>>>(bufB, W3h, W3l, b2, ns, nd, bufA, N);
    k_agg<64, 1><<<agg64, 256, 0, stream>>>(rowp, degI, srcIdx, bufA, nd, b3, out, N);
}

// Round 9
// 330.385 us; speedup vs baseline: 21.1912x; 1.0247x over previous
//
#include <hip/hip_runtime.h>

#define NN 100000
#define NB 196            // ceil(NN / 512) buckets of 512 nodes
#define CH 4096           // edges per block in k_bscatter3

typedef short short8 __attribute__((ext_vector_type(8)));
typedef unsigned short u16x8 __attribute__((ext_vector_type(8)));
typedef float f32x4 __attribute__((ext_vector_type(4)));

__device__ inline unsigned short f2bf(float x) {
    unsigned u = __float_as_uint(x);
    unsigned r = (u + 0x7FFF + ((u >> 16) & 1)) >> 16;
    return (unsigned short)r;
}
__device__ inline float bf2f(unsigned short h) {
    return __uint_as_float(((unsigned)h) << 16);
}

// ---------------- bucket histograms (src & dst) via LDS ----------------
__global__ __launch_bounds__(256) void k_bhist2(const int* __restrict__ src,
    const int* __restrict__ dst, int* __restrict__ bcntS, int* __restrict__ bcntD, int E)
{
    __shared__ int hs[NB], hd[NB];
    int t = threadIdx.x;
    if (t < NB) { hs[t] = 0; hd[t] = 0; }
    __syncthreads();
    int stride = gridDim.x * 256;
    for (int e = blockIdx.x * 256 + t; e < E; e += stride) {
        atomicAdd(&hs[src[e] >> 9], 1);
        atomicAdd(&hd[dst[e] >> 9], 1);
    }
    __syncthreads();
    if (t < NB) {
        if (hs[t]) atomicAdd(&bcntS[t], hs[t]);
        if (hd[t]) atomicAdd(&bcntD[t], hd[t]);
    }
}

// ---------------- exact bucket scans (dense tmp layout) ----------------
__global__ __launch_bounds__(256) void k_bscan2(const int* __restrict__ bcntS,
    const int* __restrict__ bcntD, int* __restrict__ bbaseS, int* __restrict__ gcurS,
    int* __restrict__ bbaseD, int* __restrict__ gcurD)
{
    __shared__ int s[256];
    int t = threadIdx.x;
    int cD = (t < NB) ? bcntD[t] : 0;
    int cS = (t < NB) ? bcntS[t] : 0;

    int v = cD;
    s[t] = v;
    __syncthreads();
#pragma unroll
    for (int off = 1; off < 256; off <<= 1) {
        int x = (t >= off) ? s[t - off] : 0;
        __syncthreads(); s[t] += x; __syncthreads();
    }
    if (t < NB) { int e = s[t] - v; bbaseD[t] = e; gcurD[t] = e; }
    __syncthreads();

    v = cS;
    s[t] = v;
    __syncthreads();
#pragma unroll
    for (int off = 1; off < 256; off <<= 1) {
        int x = (t >= off) ? s[t - off] : 0;
        __syncthreads(); s[t] += x; __syncthreads();
    }
    if (t < NB) { int e = s[t] - v; bbaseS[t] = e; gcurS[t] = e; }
}

// ---------------- one-shot counting-claim bucket scatter ----------------
__global__ __launch_bounds__(256) void k_bscatter3(const int* __restrict__ src,
    const int* __restrict__ dst, int* __restrict__ gcurD, int* __restrict__ gcurS,
    unsigned* __restrict__ tmpD, unsigned* __restrict__ tmpS, int E)
{
    __shared__ int cntD[NB], cntS[NB];
    __shared__ int runD[NB], runS[NB];
    int t = threadIdx.x;
    if (t < NB) { cntD[t] = 0; cntS[t] = 0; }
    __syncthreads();

    const int e0 = blockIdx.x * CH;
    int sv[16], dv[16];
    int offD[16], offS[16];
#pragma unroll
    for (int i = 0; i < 16; i++) {
        int e = e0 + i * 256 + t;
        if (e < E) { sv[i] = src[e]; dv[i] = dst[e]; }
    }
#pragma unroll
    for (int i = 0; i < 16; i++) {
        int e = e0 + i * 256 + t;
        if (e < E) {
            offD[i] = atomicAdd(&cntD[dv[i] >> 9], 1);
            offS[i] = atomicAdd(&cntS[sv[i] >> 9], 1);
        }
    }
    __syncthreads();
    if (t < NB) {
        int c = cntD[t];
        if (c) runD[t] = atomicAdd(&gcurD[t], c);
        c = cntS[t];
        if (c) runS[t] = atomicAdd(&gcurS[t], c);
    }
    __syncthreads();
#pragma unroll
    for (int i = 0; i < 16; i++) {
        int e = e0 + i * 256 + t;
        if (e < E) {
            int bD = dv[i] >> 9;
            tmpD[runD[bD] + offD[i]] = (unsigned)sv[i] | ((unsigned)(dv[i] & 511) << 17);
            int bS = sv[i] >> 9;
            tmpS[runS[bS] + offS[i]] = (unsigned)(sv[i] & 511);
        }
    }
}

// ---------------- src-bucket count -> ns ----------------
__global__ __launch_bounds__(256) void k_cntS(const int* __restrict__ bbaseS,
    const int* __restrict__ bcntS, const unsigned* __restrict__ tmpS,
    float* __restrict__ ns, int N)
{
    __shared__ int cnt[512];
    int b = blockIdx.x, t = threadIdx.x;
    cnt[t] = 0; cnt[t + 256] = 0;
    __syncthreads();
    int beg = bbaseS[b], end = beg + bcntS[b];
    for (int e = beg + t; e < end; e += 256)
        atomicAdd(&cnt[tmpS[e]], 1);
    __syncthreads();
    int nb = b << 9;
    for (int i = t; i < 512; i += 256) {
        int n = nb + i;
        if (n < N) ns[n] = rsqrtf(fmaxf((float)cnt[i], 1.0f));
    }
}

// ---------------- dst-bucket: degI + nd + rowptr + src-ordered CSR fill ----------------
__global__ __launch_bounds__(256) void k_csrD(const int* __restrict__ bbaseD,
    const int* __restrict__ bcntD, const unsigned* __restrict__ tmpD,
    int* __restrict__ degI, float* __restrict__ nd,
    int* __restrict__ rowptr, int* __restrict__ srcIdx, int N)
{
    __shared__ int cnt[8192];      // [dlocal][16 src-parts], 32 KB
    __shared__ int sblk[256];
    int b = blockIdx.x, t = threadIdx.x;
    for (int i = t; i < 8192; i += 256) cnt[i] = 0;
    __syncthreads();
    int beg = bbaseD[b], end = beg + bcntD[b];
    for (int e = beg + t; e < end; e += 256) {
        unsigned v = tmpD[e];
        int dl = v >> 17;
        int s  = (int)(v & 0x1FFFFu);
        atomicAdd(&cnt[(dl << 4) | (s >> 13)], 1);
    }
    __syncthreads();
    int loc[32];
    int sum = 0;
#pragma unroll
    for (int i = 0; i < 32; i++) { loc[i] = sum; sum += cnt[t * 32 + i]; }
    sblk[t] = sum;
    __syncthreads();
#pragma unroll
    for (int off = 1; off < 256; off <<= 1) {
        int x = (t >= off) ? sblk[t - off] : 0;
        __syncthreads(); sblk[t] += x; __syncthreads();
    }
    int base = beg + sblk[t] - sum;
    int v0 = loc[16];
    int v1 = sum - loc[16];
    int nb = b << 9;
    int n0 = nb + 2 * t, n1 = n0 + 1;
    if (n0 < N) { rowptr[n0] = base;           degI[n0] = v0; nd[n0] = rsqrtf(fmaxf((float)v0, 1.f)); }
    if (n1 < N) { rowptr[n1] = base + loc[16]; degI[n1] = v1; nd[n1] = rsqrtf(fmaxf((float)v1, 1.f)); }
#pragma unroll
    for (int i = 0; i < 32; i++) cnt[t * 32 + i] = base + loc[i];
    __syncthreads();
    for (int e = beg + t; e < end; e += 256) {
        unsigned v = tmpD[e];
        int dl = v >> 17;
        int s  = (int)(v & 0x1FFFFu);
        int pos = atomicAdd(&cnt[(dl << 4) | (s >> 13)], 1);
        srcIdx[pos] = s;
    }
}

// ---------------- W prep: transpose + bf16 split + XOR-swizzle ----------------
template<int DOUT>
__global__ __launch_bounds__(256) void k_prepW(const float* __restrict__ W,
    unsigned short* __restrict__ Wh, unsigned short* __restrict__ Wl)
{
    int idx = blockIdx.x * 256 + threadIdx.x;
    if (idx >= 128 * DOUT) return;
    int c = idx % DOUT;
    int k = idx / DOUT;
    float w = W[idx];
    unsigned short hi = f2bf(w);
    unsigned short lo = f2bf(w - bf2f(hi));
    int boff = c * 256 + ((2 * k) ^ ((c & 7) << 4));
    *(unsigned short*)((char*)Wh + boff) = hi;
    *(unsigned short*)((char*)Wl + boff) = lo;
}

// ---------------- MFMA GEMM layer 1: out[n][:] = (x[n][:]*ns[n]) @ W ----------------
template<int DOUT>
__global__ __launch_bounds__(256) void k_gemm_mfma(
    const float* __restrict__ in,
    const unsigned short* __restrict__ Wth, const unsigned short* __restrict__ Wtl,
    const float* __restrict__ ns,
    unsigned short* __restrict__ out, int N)
{
    constexpr int NT = DOUT / 16;
    __shared__ __align__(16) unsigned short Wh[DOUT * 128];
    __shared__ __align__(16) unsigned short Wl[DOUT * 128];

    const int t = threadIdx.x;
    const int w = t >> 6, l = t & 63;

#pragma unroll
    for (int i = 0; i < DOUT * 256 / 4096; i++) {
        int off = i * 4096 + t * 16;
        *(float4*)((char*)Wh + off) = *(const float4*)((const char*)Wth + off);
        *(float4*)((char*)Wl + off) = *(const float4*)((const char*)Wtl + off);
    }

    const int rl   = l & 15;
    const int kgrp = l >> 4;
    const int row  = blockIdx.x * 64 + w * 16 + rl;
    const int rowc = row < N ? row : N - 1;
    const float* arow = in + (size_t)rowc * 128;

    float av[4][8];
#pragma unroll
    for (int ks = 0; ks < 4; ks++) {
        int kb = ks * 32 + kgrp * 8;
        float4 v0 = *(const float4*)(arow + kb);
        float4 v1 = *(const float4*)(arow + kb + 4);
        av[ks][0] = v0.x; av[ks][1] = v0.y; av[ks][2] = v0.z; av[ks][3] = v0.w;
        av[ks][4] = v1.x; av[ks][5] = v1.y; av[ks][6] = v1.z; av[ks][7] = v1.w;
    }
    float nsv = ns[rowc];
    short8 Ah[4], Al[4];
#pragma unroll
    for (int ks = 0; ks < 4; ks++)
#pragma unroll
        for (int j = 0; j < 8; j++) {
            float v = av[ks][j] * nsv;
            unsigned short hi = f2bf(v);
            Ah[ks][j] = (short)hi;
            Al[ks][j] = (short)f2bf(v - bf2f(hi));
        }

    __syncthreads();

    f32x4 acc[NT];
#pragma unroll
    for (int tt = 0; tt < NT; tt++) acc[tt] = (f32x4){0.f, 0.f, 0.f, 0.f};

#pragma unroll
    for (int ks = 0; ks < 4; ks++) {
        int kbyte = ks * 64 + kgrp * 16;
#pragma unroll
        for (int tt = 0; tt < NT; tt++) {
            int c = tt * 16 + rl;
            int boff = c * 256 + (kbyte ^ ((c & 7) << 4));
            short8 Bh = *(short8*)((char*)Wh + boff);
            short8 Bl = *(short8*)((char*)Wl + boff);
            acc[tt] = __builtin_amdgcn_mfma_f32_16x16x32_bf16(Ah[ks], Bh, acc[tt], 0, 0, 0);
            acc[tt] = __builtin_amdgcn_mfma_f32_16x16x32_bf16(Al[ks], Bh, acc[tt], 0, 0, 0);
            acc[tt] = __builtin_amdgcn_mfma_f32_16x16x32_bf16(Ah[ks], Bl, acc[tt], 0, 0, 0);
        }
    }

    const int orow = blockIdx.x * 64 + w * 16 + kgrp * 4;
#pragma unroll
    for (int r = 0; r < 4; r++) {
        if (orow + r < N) {
#pragma unroll
            for (int tt = 0; tt < NT; tt++)
                out[(size_t)(orow + r) * DOUT + tt * 16 + rl] = f2bf(acc[tt][r]);
        }
    }
}

// ---------------- FUSED gather-GEMM: out[n][:] = relu(Agg(h)[n]*nd[n]+b)*ns[n] @ W ----------------
// 512 threads = 8 waves, BM = 128 rows. h is bf16 with row stride 128.
template<int DOUT>
__global__ __launch_bounds__(512, 4) void k_gemm_gather(
    const int* __restrict__ rowptr, const int* __restrict__ degI,
    const int* __restrict__ srcIdx, const unsigned short* __restrict__ h,
    const unsigned short* __restrict__ Wth, const unsigned short* __restrict__ Wtl,
    const float* __restrict__ bprev,
    const float* __restrict__ ns, const float* __restrict__ nd,
    unsigned short* __restrict__ out, int N)
{
    constexpr int NT = DOUT / 16;
    __shared__ __align__(16) unsigned short Wh[DOUT * 128];
    __shared__ __align__(16) unsigned short Wl[DOUT * 128];

    const int t = threadIdx.x;
    const int w = t >> 6, l = t & 63;

#pragma unroll
    for (int i = 0; i < DOUT * 16 / 512; i++) {
        int off = (i * 512 + t) * 16;
        *(float4*)((char*)Wh + off) = *(const float4*)((const char*)Wth + off);
        *(float4*)((char*)Wl + off) = *(const float4*)((const char*)Wtl + off);
    }

    const int rl   = l & 15;
    const int kgrp = l >> 4;          // 0..3: owns channels ks*32 + kgrp*8, ks=0..3
    const int row  = blockIdx.x * 128 + w * 16 + rl;

    // ---- gather + sum (f32) ----
    float facc[4][8];
#pragma unroll
    for (int ks = 0; ks < 4; ks++)
#pragma unroll
        for (int j = 0; j < 8; j++) facc[ks][j] = 0.f;

    if (row < N) {
        int beg = rowptr[row];
        int end = beg + degI[row];
        for (int e = beg; e < end; e++) {
            int s = srcIdx[e];
            const u16x8* hp = (const u16x8*)(h + (size_t)s * 128);
#pragma unroll
            for (int ks = 0; ks < 4; ks++) {
                u16x8 v = hp[ks * 4 + kgrp];
#pragma unroll
                for (int j = 0; j < 8; j++) facc[ks][j] += bf2f(v[j]);
            }
        }
    }

    // ---- epilogue + bf16 split ----
    short8 Ah[4], Al[4];
    {
        float ndv = 0.f, nsv = 0.f;
        if (row < N) { ndv = nd[row]; nsv = ns[row]; }
#pragma unroll
        for (int ks = 0; ks < 4; ks++) {
            int kb = ks * 32 + kgrp * 8;
            float4 b0 = *(const float4*)(bprev + kb);
            float4 b1 = *(const float4*)(bprev + kb + 4);
            float bb[8] = {b0.x, b0.y, b0.z, b0.w, b1.x, b1.y, b1.z, b1.w};
#pragma unroll
            for (int j = 0; j < 8; j++) {
                float v = fmaxf(facc[ks][j] * ndv + bb[j], 0.f) * nsv;
                unsigned short hi = f2bf(v);
                Ah[ks][j] = (short)hi;
                Al[ks][j] = (short)f2bf(v - bf2f(hi));
            }
        }
    }

    __syncthreads();

    // ---- MFMA ----
    f32x4 acc[NT];
#pragma unroll
    for (int tt = 0; tt < NT; tt++) acc[tt] = (f32x4){0.f, 0.f, 0.f, 0.f};

#pragma unroll
    for (int ks = 0; ks < 4; ks++) {
        int kbyte = ks * 64 + kgrp * 16;
#pragma unroll
        for (int tt = 0; tt < NT; tt++) {
            int c = tt * 16 + rl;
            int boff = c * 256 + (kbyte ^ ((c & 7) << 4));
            short8 Bh = *(short8*)((char*)Wh + boff);
            short8 Bl = *(short8*)((char*)Wl + boff);
            acc[tt] = __builtin_amdgcn_mfma_f32_16x16x32_bf16(Ah[ks], Bh, acc[tt], 0, 0, 0);
            acc[tt] = __builtin_amdgcn_mfma_f32_16x16x32_bf16(Al[ks], Bh, acc[tt], 0, 0, 0);
            acc[tt] = __builtin_amdgcn_mfma_f32_16x16x32_bf16(Ah[ks], Bl, acc[tt], 0, 0, 0);
        }
    }

    const int orow = blockIdx.x * 128 + w * 16 + kgrp * 4;
#pragma unroll
    for (int r = 0; r < 4; r++) {
        if (orow + r < N) {
#pragma unroll
            for (int tt = 0; tt < NT; tt++)
                out[(size_t)(orow + r) * DOUT + tt * 16 + rl] = f2bf(acc[tt][r]);
        }
    }
}

// ---------------- final aggregation (bf16 gather, f32 accumulate, epilogue) ----------------
template<int D>
__global__ __launch_bounds__(256) void k_agg_final(
    const int* __restrict__ rowptr, const int* __restrict__ cnt,
    const int* __restrict__ srcIdx, const unsigned short* __restrict__ h,
    const float* __restrict__ nd, const float* __restrict__ b3,
    float* __restrict__ m, int N)
{
    constexpr int TPN = D / 8;
    constexpr int NPB = 256 / TPN;
    int t = threadIdx.x;
    int node = blockIdx.x * NPB + t / TPN;
    if (node >= N) return;
    int c = (t % TPN) * 8;

    int beg = rowptr[node];
    int end = beg + cnt[node];
    float acc[8] = {0.f, 0.f, 0.f, 0.f, 0.f, 0.f, 0.f, 0.f};
    for (int e = beg; e < end; e++) {
        int s = srcIdx[e];
        u16x8 v = *(const u16x8*)&h[(size_t)s * D + c];
#pragma unroll
        for (int j = 0; j < 8; j++) acc[j] += bf2f(v[j]);
    }
    float ndv = nd[node];
#pragma unroll
    for (int j = 0; j < 8; j++) acc[j] = acc[j] * ndv + b3[c + j];
    float4* mp = (float4*)&m[(size_t)node * D + c];
    mp[0] = make_float4(acc[0], acc[1], acc[2], acc[3]);
    mp[1] = make_float4(acc[4], acc[5], acc[6], acc[7]);
}

extern "C" void kernel_launch(void* const* d_in, const int* in_sizes, int n_in,
                              void* d_out, int out_size, void* d_ws, size_t ws_size,
                              hipStream_t stream) {
    const float* x  = (const float*)d_in[0];
    const int*   src = (const int*)d_in[1];
    const int*   dst = (const int*)d_in[2];
    const float* W1 = (const float*)d_in[3];
    const float* b1 = (const float*)d_in[4];
    const float* W2 = (const float*)d_in[5];
    const float* b2 = (const float*)d_in[6];
    const float* W3 = (const float*)d_in[7];
    const float* b3 = (const float*)d_in[8];
    float* out = (float*)d_out;

    const int N = NN;
    const int E = in_sizes[1];

    char* ws = (char*)d_ws;
    unsigned short* bufA = (unsigned short*)ws;                 // h1 / h3 bf16 (aliases tmpD)
    unsigned short* bufB = (unsigned short*)(ws + (size_t)N * 128 * 4); // h2 bf16 (aliases tmpS)
    unsigned* tmpD = (unsigned*)bufA;                           // consumed by k_csrD before gemm1 writes bufA
    unsigned* tmpS = (unsigned*)bufB;                           // consumed by k_cntS before gemm2F writes bufB
    char*  p     = ws + (size_t)N * 128 * 4 * 2;
    float* ns    = (float*)p;              p += (size_t)N * 4;
    float* nd    = (float*)p;              p += (size_t)N * 4;
    int*   degI  = (int*)p;                p += (size_t)N * 4;
    int*   rowp  = (int*)p;                p += (size_t)N * 4;
    int*   srcIdx= (int*)p;                p += (size_t)E * 4;
    unsigned short* W1h = (unsigned short*)p; p += 128 * 128 * 2;
    unsigned short* W1l = (unsigned short*)p; p += 128 * 128 * 2;
    unsigned short* W2h = (unsigned short*)p; p += 128 * 128 * 2;
    unsigned short* W2l = (unsigned short*)p; p += 128 * 128 * 2;
    unsigned short* W3h = (unsigned short*)p; p += 64 * 128 * 2;
    unsigned short* W3l = (unsigned short*)p; p += 64 * 128 * 2;
    int* bcntS = (int*)p;                  p += 256 * 4;
    int* bcntD = (int*)p;                  p += 256 * 4;
    int* bbaseS= (int*)p;                  p += 256 * 4;
    int* bbaseD= (int*)p;                  p += 256 * 4;
    int* gcurS = (int*)p;                  p += 256 * 4;
    int* gcurD = (int*)p;                  p += 256 * 4;

    // W prep (independent)
    k_prepW<128><<<64, 256, 0, stream>>>(W1, W1h, W1l);
    k_prepW<128><<<64, 256, 0, stream>>>(W2, W2h, W2l);
    k_prepW<64><<<32, 256, 0, stream>>>(W3, W3h, W3l);

    // bucketed degree/CSR pipeline (no per-edge global atomics)
    hipMemsetAsync(bcntS, 0, 2 * 256 * 4, stream);
    k_bhist2<<<192, 256, 0, stream>>>(src, dst, bcntS, bcntD, E);
    k_bscan2<<<1, 256, 0, stream>>>(bcntS, bcntD, bbaseS, gcurS, bbaseD, gcurD);
    k_bscatter3<<<(E + CH - 1) / CH, 256, 0, stream>>>(src, dst, gcurD, gcurS, tmpD, tmpS, E);
    k_cntS<<<NB, 256, 0, stream>>>(bbaseS, bcntS, tmpS, ns, N);
    k_csrD<<<NB, 256, 0, stream>>>(bbaseD, bcntD, tmpD, degI, nd, rowp, srcIdx, N);

    const int gemm_grid  = (N + 63) / 64;
    const int fused_grid = (N + 127) / 128;
    const int agg64      = (N + 31) / 32;

    // ---- layer 1: h1 = (x*ns) @ W1 ----
    k_gemm_mfma<128><<<gemm_grid, 256, 0, stream>>>(x, W1h, W1l, ns, bufA, N);

    // ---- layer 2 fused: h2 = relu(Agg(h1)*nd + b1)*ns @ W2 ----
    k_gemm_gather<128><<<fused_grid, 512, 0, stream>>>(rowp, degI, srcIdx, bufA,
        W2h, W2l, b1, ns, nd, bufB, N);

    // ---- layer 3 fused: h3 = relu(Agg(h2)*nd + b2)*ns @ W3 ----
    k_gemm_gather<64><<<fused_grid, 512, 0, stream>>>(rowp, degI, srcIdx, bufB,
        W3h, W3l, b2, ns, nd, bufA, N);

    // ---- final: out = Agg(h3)*nd + b3 ----
    k_agg_final<64><<<agg64, 256, 0, stream>>>(rowp, degI, srcIdx, bufA, nd, b3, out, N);
}

// Round 10
// 330.075 us; speedup vs baseline: 21.2111x; 1.0009x over previous
//
#include <hip/hip_runtime.h>

#define NN 100000
#define NB 196            // ceil(NN / 512) buckets of 512 nodes
#define CH 4096           // edges per block in k_bscatter3

typedef short short8 __attribute__((ext_vector_type(8)));
typedef unsigned short u16x8 __attribute__((ext_vector_type(8)));
typedef float f32x4 __attribute__((ext_vector_type(4)));

__device__ inline unsigned short f2bf(float x) {
    unsigned u = __float_as_uint(x);
    unsigned r = (u + 0x7FFF + ((u >> 16) & 1)) >> 16;
    return (unsigned short)r;
}
__device__ inline float bf2f(unsigned short h) {
    return __uint_as_float(((unsigned)h) << 16);
}

// ---------------- bucket histograms (src & dst) via LDS ----------------
__global__ __launch_bounds__(256) void k_bhist2(const int* __restrict__ src,
    const int* __restrict__ dst, int* __restrict__ bcntS, int* __restrict__ bcntD, int E)
{
    __shared__ int hs[NB], hd[NB];
    int t = threadIdx.x;
    if (t < NB) { hs[t] = 0; hd[t] = 0; }
    __syncthreads();
    int stride = gridDim.x * 256;
    for (int e = blockIdx.x * 256 + t; e < E; e += stride) {
        atomicAdd(&hs[src[e] >> 9], 1);
        atomicAdd(&hd[dst[e] >> 9], 1);
    }
    __syncthreads();
    if (t < NB) {
        if (hs[t]) atomicAdd(&bcntS[t], hs[t]);
        if (hd[t]) atomicAdd(&bcntD[t], hd[t]);
    }
}

// ---------------- exact bucket scans (dense tmp layout) ----------------
__global__ __launch_bounds__(256) void k_bscan2(const int* __restrict__ bcntS,
    const int* __restrict__ bcntD, int* __restrict__ bbaseS, int* __restrict__ gcurS,
    int* __restrict__ bbaseD, int* __restrict__ gcurD)
{
    __shared__ int s[256];
    int t = threadIdx.x;
    int cD = (t < NB) ? bcntD[t] : 0;
    int cS = (t < NB) ? bcntS[t] : 0;

    int v = cD;
    s[t] = v;
    __syncthreads();
#pragma unroll
    for (int off = 1; off < 256; off <<= 1) {
        int x = (t >= off) ? s[t - off] : 0;
        __syncthreads(); s[t] += x; __syncthreads();
    }
    if (t < NB) { int e = s[t] - v; bbaseD[t] = e; gcurD[t] = e; }
    __syncthreads();

    v = cS;
    s[t] = v;
    __syncthreads();
#pragma unroll
    for (int off = 1; off < 256; off <<= 1) {
        int x = (t >= off) ? s[t - off] : 0;
        __syncthreads(); s[t] += x; __syncthreads();
    }
    if (t < NB) { int e = s[t] - v; bbaseS[t] = e; gcurS[t] = e; }
}

// ---------------- one-shot counting-claim bucket scatter ----------------
__global__ __launch_bounds__(256) void k_bscatter3(const int* __restrict__ src,
    const int* __restrict__ dst, int* __restrict__ gcurD, int* __restrict__ gcurS,
    unsigned* __restrict__ tmpD, unsigned* __restrict__ tmpS, int E)
{
    __shared__ int cntD[NB], cntS[NB];
    __shared__ int runD[NB], runS[NB];
    int t = threadIdx.x;
    if (t < NB) { cntD[t] = 0; cntS[t] = 0; }
    __syncthreads();

    const int e0 = blockIdx.x * CH;
    int sv[16], dv[16];
    int offD[16], offS[16];
#pragma unroll
    for (int i = 0; i < 16; i++) {
        int e = e0 + i * 256 + t;
        if (e < E) { sv[i] = src[e]; dv[i] = dst[e]; }
    }
#pragma unroll
    for (int i = 0; i < 16; i++) {
        int e = e0 + i * 256 + t;
        if (e < E) {
            offD[i] = atomicAdd(&cntD[dv[i] >> 9], 1);
            offS[i] = atomicAdd(&cntS[sv[i] >> 9], 1);
        }
    }
    __syncthreads();
    if (t < NB) {
        int c = cntD[t];
        if (c) runD[t] = atomicAdd(&gcurD[t], c);
        c = cntS[t];
        if (c) runS[t] = atomicAdd(&gcurS[t], c);
    }
    __syncthreads();
#pragma unroll
    for (int i = 0; i < 16; i++) {
        int e = e0 + i * 256 + t;
        if (e < E) {
            int bD = dv[i] >> 9;
            tmpD[runD[bD] + offD[i]] = (unsigned)sv[i] | ((unsigned)(dv[i] & 511) << 17);
            int bS = sv[i] >> 9;
            tmpS[runS[bS] + offS[i]] = (unsigned)(sv[i] & 511);
        }
    }
}

// ---------------- src-bucket count -> ns ----------------
__global__ __launch_bounds__(256) void k_cntS(const int* __restrict__ bbaseS,
    const int* __restrict__ bcntS, const unsigned* __restrict__ tmpS,
    float* __restrict__ ns, int N)
{
    __shared__ int cnt[512];
    int b = blockIdx.x, t = threadIdx.x;
    cnt[t] = 0; cnt[t + 256] = 0;
    __syncthreads();
    int beg = bbaseS[b], end = beg + bcntS[b];
    for (int e = beg + t; e < end; e += 256)
        atomicAdd(&cnt[tmpS[e]], 1);
    __syncthreads();
    int nb = b << 9;
    for (int i = t; i < 512; i += 256) {
        int n = nb + i;
        if (n < N) ns[n] = rsqrtf(fmaxf((float)cnt[i], 1.0f));
    }
}

// ---------------- dst-bucket: degI + nd + rowptr + src-ordered CSR fill ----------------
__global__ __launch_bounds__(256) void k_csrD(const int* __restrict__ bbaseD,
    const int* __restrict__ bcntD, const unsigned* __restrict__ tmpD,
    int* __restrict__ degI, float* __restrict__ nd,
    int* __restrict__ rowptr, int* __restrict__ srcIdx, int N)
{
    __shared__ int cnt[8192];      // [dlocal][16 src-parts], 32 KB
    __shared__ int sblk[256];
    int b = blockIdx.x, t = threadIdx.x;
    for (int i = t; i < 8192; i += 256) cnt[i] = 0;
    __syncthreads();
    int beg = bbaseD[b], end = beg + bcntD[b];
    for (int e = beg + t; e < end; e += 256) {
        unsigned v = tmpD[e];
        int dl = v >> 17;
        int s  = (int)(v & 0x1FFFFu);
        atomicAdd(&cnt[(dl << 4) | (s >> 13)], 1);
    }
    __syncthreads();
    int loc[32];
    int sum = 0;
#pragma unroll
    for (int i = 0; i < 32; i++) { loc[i] = sum; sum += cnt[t * 32 + i]; }
    sblk[t] = sum;
    __syncthreads();
#pragma unroll
    for (int off = 1; off < 256; off <<= 1) {
        int x = (t >= off) ? sblk[t - off] : 0;
        __syncthreads(); sblk[t] += x; __syncthreads();
    }
    int base = beg + sblk[t] - sum;
    int v0 = loc[16];
    int v1 = sum - loc[16];
    int nb = b << 9;
    int n0 = nb + 2 * t, n1 = n0 + 1;
    if (n0 < N) { rowptr[n0] = base;           degI[n0] = v0; nd[n0] = rsqrtf(fmaxf((float)v0, 1.f)); }
    if (n1 < N) { rowptr[n1] = base + loc[16]; degI[n1] = v1; nd[n1] = rsqrtf(fmaxf((float)v1, 1.f)); }
#pragma unroll
    for (int i = 0; i < 32; i++) cnt[t * 32 + i] = base + loc[i];
    __syncthreads();
    for (int e = beg + t; e < end; e += 256) {
        unsigned v = tmpD[e];
        int dl = v >> 17;
        int s  = (int)(v & 0x1FFFFu);
        int pos = atomicAdd(&cnt[(dl << 4) | (s >> 13)], 1);
        srcIdx[pos] = s;
    }
}

// ---------------- W prep: transpose + bf16 split + XOR-swizzle ----------------
template<int DOUT>
__global__ __launch_bounds__(256) void k_prepW(const float* __restrict__ W,
    unsigned short* __restrict__ Wh, unsigned short* __restrict__ Wl)
{
    int idx = blockIdx.x * 256 + threadIdx.x;
    if (idx >= 128 * DOUT) return;
    int c = idx % DOUT;
    int k = idx / DOUT;
    float w = W[idx];
    unsigned short hi = f2bf(w);
    unsigned short lo = f2bf(w - bf2f(hi));
    int boff = c * 256 + ((2 * k) ^ ((c & 7) << 4));
    *(unsigned short*)((char*)Wh + boff) = hi;
    *(unsigned short*)((char*)Wl + boff) = lo;
}

// ---------------- MFMA GEMM layer 1: out[n][:] = (x[n][:]*ns[n]) @ W ----------------
template<int DOUT>
__global__ __launch_bounds__(256) void k_gemm_mfma(
    const float* __restrict__ in,
    const unsigned short* __restrict__ Wth, const unsigned short* __restrict__ Wtl,
    const float* __restrict__ ns,
    unsigned short* __restrict__ out, int N)
{
    constexpr int NT = DOUT / 16;
    __shared__ __align__(16) unsigned short Wh[DOUT * 128];
    __shared__ __align__(16) unsigned short Wl[DOUT * 128];

    const int t = threadIdx.x;
    const int w = t >> 6, l = t & 63;

#pragma unroll
    for (int i = 0; i < DOUT * 256 / 4096; i++) {
        int off = i * 4096 + t * 16;
        *(float4*)((char*)Wh + off) = *(const float4*)((const char*)Wth + off);
        *(float4*)((char*)Wl + off) = *(const float4*)((const char*)Wtl + off);
    }

    const int rl   = l & 15;
    const int kgrp = l >> 4;
    const int row  = blockIdx.x * 64 + w * 16 + rl;
    const int rowc = row < N ? row : N - 1;
    const float* arow = in + (size_t)rowc * 128;

    float av[4][8];
#pragma unroll
    for (int ks = 0; ks < 4; ks++) {
        int kb = ks * 32 + kgrp * 8;
        float4 v0 = *(const float4*)(arow + kb);
        float4 v1 = *(const float4*)(arow + kb + 4);
        av[ks][0] = v0.x; av[ks][1] = v0.y; av[ks][2] = v0.z; av[ks][3] = v0.w;
        av[ks][4] = v1.x; av[ks][5] = v1.y; av[ks][6] = v1.z; av[ks][7] = v1.w;
    }
    float nsv = ns[rowc];
    short8 Ah[4], Al[4];
#pragma unroll
    for (int ks = 0; ks < 4; ks++)
#pragma unroll
        for (int j = 0; j < 8; j++) {
            float v = av[ks][j] * nsv;
            unsigned short hi = f2bf(v);
            Ah[ks][j] = (short)hi;
            Al[ks][j] = (short)f2bf(v - bf2f(hi));
        }

    __syncthreads();

    f32x4 acc[NT];
#pragma unroll
    for (int tt = 0; tt < NT; tt++) acc[tt] = (f32x4){0.f, 0.f, 0.f, 0.f};

#pragma unroll
    for (int ks = 0; ks < 4; ks++) {
        int kbyte = ks * 64 + kgrp * 16;
#pragma unroll
        for (int tt = 0; tt < NT; tt++) {
            int c = tt * 16 + rl;
            int boff = c * 256 + (kbyte ^ ((c & 7) << 4));
            short8 Bh = *(short8*)((char*)Wh + boff);
            short8 Bl = *(short8*)((char*)Wl + boff);
            acc[tt] = __builtin_amdgcn_mfma_f32_16x16x32_bf16(Ah[ks], Bh, acc[tt], 0, 0, 0);
            acc[tt] = __builtin_amdgcn_mfma_f32_16x16x32_bf16(Al[ks], Bh, acc[tt], 0, 0, 0);
            acc[tt] = __builtin_amdgcn_mfma_f32_16x16x32_bf16(Ah[ks], Bl, acc[tt], 0, 0, 0);
        }
    }

    const int orow = blockIdx.x * 64 + w * 16 + kgrp * 4;
#pragma unroll
    for (int r = 0; r < 4; r++) {
        if (orow + r < N) {
#pragma unroll
            for (int tt = 0; tt < NT; tt++)
                out[(size_t)(orow + r) * DOUT + tt * 16 + rl] = f2bf(acc[tt][r]);
        }
    }
}

// ---------------- FUSED gather-GEMM, phased W staging (32 KB LDS) ----------------
// out[n][:] = relu(Agg(h)[n]*nd[n]+b)*ns[n] @ W ; 256 thr / BM=64 / 5 blocks/CU
template<int DOUT>
__global__ __launch_bounds__(256, 5) void k_gemm_gather(
    const int* __restrict__ rowptr, const int* __restrict__ degI,
    const int* __restrict__ srcIdx, const unsigned short* __restrict__ h,
    const unsigned short* __restrict__ Wth, const unsigned short* __restrict__ Wtl,
    const float* __restrict__ bprev,
    const float* __restrict__ ns, const float* __restrict__ nd,
    unsigned short* __restrict__ out, int N)
{
    constexpr int NT = DOUT / 16;
    constexpr int PH = DOUT / 64;              // 2 (DOUT=128) or 1 (DOUT=64)
    __shared__ __align__(16) unsigned short Wh[64 * 128];   // 16 KB
    __shared__ __align__(16) unsigned short Wl[64 * 128];   // 16 KB

    const int t = threadIdx.x;
    const int w = t >> 6, l = t & 63;
    const int rl   = l & 15;
    const int kgrp = l >> 4;
    const int row  = blockIdx.x * 64 + w * 16 + rl;

    // ---- gather + sum (f32) ----
    float facc[4][8];
#pragma unroll
    for (int ks = 0; ks < 4; ks++)
#pragma unroll
        for (int j = 0; j < 8; j++) facc[ks][j] = 0.f;

    if (row < N) {
        int beg = rowptr[row];
        int end = beg + degI[row];
        for (int e = beg; e < end; e++) {
            int s = srcIdx[e];
            const u16x8* hp = (const u16x8*)(h + (size_t)s * 128);
#pragma unroll
            for (int ks = 0; ks < 4; ks++) {
                u16x8 v = hp[ks * 4 + kgrp];
#pragma unroll
                for (int j = 0; j < 8; j++) facc[ks][j] += bf2f(v[j]);
            }
        }
    }

    // ---- epilogue + bf16 split ----
    short8 Ah[4], Al[4];
    {
        float ndv = 0.f, nsv = 0.f;
        if (row < N) { ndv = nd[row]; nsv = ns[row]; }
#pragma unroll
        for (int ks = 0; ks < 4; ks++) {
            int kb = ks * 32 + kgrp * 8;
            float4 b0 = *(const float4*)(bprev + kb);
            float4 b1 = *(const float4*)(bprev + kb + 4);
            float bb[8] = {b0.x, b0.y, b0.z, b0.w, b1.x, b1.y, b1.z, b1.w};
#pragma unroll
            for (int j = 0; j < 8; j++) {
                float v = fmaxf(facc[ks][j] * ndv + bb[j], 0.f) * nsv;
                unsigned short hi = f2bf(v);
                Ah[ks][j] = (short)hi;
                Al[ks][j] = (short)f2bf(v - bf2f(hi));
            }
        }
    }

    // ---- phased MFMA: stage 64 W columns at a time ----
    f32x4 acc[NT];
#pragma unroll
    for (int tt = 0; tt < NT; tt++) acc[tt] = (f32x4){0.f, 0.f, 0.f, 0.f};

#pragma unroll
    for (int ph = 0; ph < PH; ph++) {
        __syncthreads();   // previous phase's reads done / gather regs ready
#pragma unroll
        for (int i = 0; i < 4; i++) {
            int off = (i * 256 + t) * 16;   // 16 KB per buffer
            *(float4*)((char*)Wh + off) = *(const float4*)((const char*)Wth + ph * 16384 + off);
            *(float4*)((char*)Wl + off) = *(const float4*)((const char*)Wtl + ph * 16384 + off);
        }
        __syncthreads();
#pragma unroll
        for (int ks = 0; ks < 4; ks++) {
            int kbyte = ks * 64 + kgrp * 16;
#pragma unroll
            for (int tt = 0; tt < 4; tt++) {
                int c = tt * 16 + rl;       // column within phase
                int boff = c * 256 + (kbyte ^ ((c & 7) << 4));
                short8 Bh = *(short8*)((char*)Wh + boff);
                short8 Bl = *(short8*)((char*)Wl + boff);
                acc[ph * 4 + tt] = __builtin_amdgcn_mfma_f32_16x16x32_bf16(Ah[ks], Bh, acc[ph * 4 + tt], 0, 0, 0);
                acc[ph * 4 + tt] = __builtin_amdgcn_mfma_f32_16x16x32_bf16(Al[ks], Bh, acc[ph * 4 + tt], 0, 0, 0);
                acc[ph * 4 + tt] = __builtin_amdgcn_mfma_f32_16x16x32_bf16(Ah[ks], Bl, acc[ph * 4 + tt], 0, 0, 0);
            }
        }
    }

    // ---- store: global col = tt*16 + rl (tt = ph*4 + tt_local) ----
    const int orow = blockIdx.x * 64 + w * 16 + kgrp * 4;
#pragma unroll
    for (int r = 0; r < 4; r++) {
        if (orow + r < N) {
#pragma unroll
            for (int tt = 0; tt < NT; tt++)
                out[(size_t)(orow + r) * DOUT + tt * 16 + rl] = f2bf(acc[tt][r]);
        }
    }
}

// ---------------- final aggregation (bf16 gather, f32 accumulate, epilogue) ----------------
template<int D>
__global__ __launch_bounds__(256) void k_agg_final(
    const int* __restrict__ rowptr, const int* __restrict__ cnt,
    const int* __restrict__ srcIdx, const unsigned short* __restrict__ h,
    const float* __restrict__ nd, const float* __restrict__ b3,
    float* __restrict__ m, int N)
{
    constexpr int TPN = D / 8;
    constexpr int NPB = 256 / TPN;
    int t = threadIdx.x;
    int node = blockIdx.x * NPB + t / TPN;
    if (node >= N) return;
    int c = (t % TPN) * 8;

    int beg = rowptr[node];
    int end = beg + cnt[node];
    float acc[8] = {0.f, 0.f, 0.f, 0.f, 0.f, 0.f, 0.f, 0.f};
    for (int e = beg; e < end; e++) {
        int s = srcIdx[e];
        u16x8 v = *(const u16x8*)&h[(size_t)s * D + c];
#pragma unroll
        for (int j = 0; j < 8; j++) acc[j] += bf2f(v[j]);
    }
    float ndv = nd[node];
#pragma unroll
    for (int j = 0; j < 8; j++) acc[j] = acc[j] * ndv + b3[c + j];
    float4* mp = (float4*)&m[(size_t)node * D + c];
    mp[0] = make_float4(acc[0], acc[1], acc[2], acc[3]);
    mp[1] = make_float4(acc[4], acc[5], acc[6], acc[7]);
}

extern "C" void kernel_launch(void* const* d_in, const int* in_sizes, int n_in,
                              void* d_out, int out_size, void* d_ws, size_t ws_size,
                              hipStream_t stream) {
    const float* x  = (const float*)d_in[0];
    const int*   src = (const int*)d_in[1];
    const int*   dst = (const int*)d_in[2];
    const float* W1 = (const float*)d_in[3];
    const float* b1 = (const float*)d_in[4];
    const float* W2 = (const float*)d_in[5];
    const float* b2 = (const float*)d_in[6];
    const float* W3 = (const float*)d_in[7];
    const float* b3 = (const float*)d_in[8];
    float* out = (float*)d_out;

    const int N = NN;
    const int E = in_sizes[1];

    char* ws = (char*)d_ws;
    unsigned short* bufA = (unsigned short*)ws;                 // h1 / h3 bf16 (aliases tmpD)
    unsigned short* bufB = (unsigned short*)(ws + (size_t)N * 128 * 4); // h2 bf16 (aliases tmpS)
    unsigned* tmpD = (unsigned*)bufA;                           // consumed by k_csrD before gemm1 writes bufA
    unsigned* tmpS = (unsigned*)bufB;                           // consumed by k_cntS before gemm2F writes bufB
    char*  p     = ws + (size_t)N * 128 * 4 * 2;
    float* ns    = (float*)p;              p += (size_t)N * 4;
    float* nd    = (float*)p;              p += (size_t)N * 4;
    int*   degI  = (int*)p;                p += (size_t)N * 4;
    int*   rowp  = (int*)p;                p += (size_t)N * 4;
    int*   srcIdx= (int*)p;                p += (size_t)E * 4;
    unsigned short* W1h = (unsigned short*)p; p += 128 * 128 * 2;
    unsigned short* W1l = (unsigned short*)p; p += 128 * 128 * 2;
    unsigned short* W2h = (unsigned short*)p; p += 128 * 128 * 2;
    unsigned short* W2l = (unsigned short*)p; p += 128 * 128 * 2;
    unsigned short* W3h = (unsigned short*)p; p += 64 * 128 * 2;
    unsigned short* W3l = (unsigned short*)p; p += 64 * 128 * 2;
    int* bcntS = (int*)p;                  p += 256 * 4;
    int* bcntD = (int*)p;                  p += 256 * 4;
    int* bbaseS= (int*)p;                  p += 256 * 4;
    int* bbaseD= (int*)p;                  p += 256 * 4;
    int* gcurS = (int*)p;                  p += 256 * 4;
    int* gcurD = (int*)p;                  p += 256 * 4;

    // W prep (independent)
    k_prepW<128><<<64, 256, 0, stream>>>(W1, W1h, W1l);
    k_prepW<128><<<64, 256, 0, stream>>>(W2, W2h, W2l);
    k_prepW<64><<<32, 256, 0, stream>>>(W3, W3h, W3l);

    // bucketed degree/CSR pipeline (no per-edge global atomics)
    hipMemsetAsync(bcntS, 0, 2 * 256 * 4, stream);
    k_bhist2<<<192, 256, 0, stream>>>(src, dst, bcntS, bcntD, E);
    k_bscan2<<<1, 256, 0, stream>>>(bcntS, bcntD, bbaseS, gcurS, bbaseD, gcurD);
    k_bscatter3<<<(E + CH - 1) / CH, 256, 0, stream>>>(src, dst, gcurD, gcurS, tmpD, tmpS, E);
    k_cntS<<<NB, 256, 0, stream>>>(bbaseS, bcntS, tmpS, ns, N);
    k_csrD<<<NB, 256, 0, stream>>>(bbaseD, bcntD, tmpD, degI, nd, rowp, srcIdx, N);

    const int gemm_grid  = (N + 63) / 64;
    const int agg64      = (N + 31) / 32;

    // ---- layer 1: h1 = (x*ns) @ W1 ----
    k_gemm_mfma<128><<<gemm_grid, 256, 0, stream>>>(x, W1h, W1l, ns, bufA, N);

    // ---- layer 2 fused: h2 = relu(Agg(h1)*nd + b1)*ns @ W2 ----
    k_gemm_gather<128><<<gemm_grid, 256, 0, stream>>>(rowp, degI, srcIdx, bufA,
        W2h, W2l, b1, ns, nd, bufB, N);

    // ---- layer 3 fused: h3 = relu(Agg(h2)*nd + b2)*ns @ W3 ----
    k_gemm_gather<64><<<gemm_grid, 256, 0, stream>>>(rowp, degI, srcIdx, bufB,
        W3h, W3l, b2, ns, nd, bufA, N);

    // ---- final: out = Agg(h3)*nd + b3 ----
    k_agg_final<64><<<agg64, 256, 0, stream>>>(rowp, degI, srcIdx, bufA, nd, b3, out, N);
}